// Round 14
// baseline (466.895 us; speedup 1.0000x reference)
//
#include <hip/hip_runtime.h>
#include <math.h>

#define BB 2
#define CCH 8
#define BINS 1024
#define WW 512
#define HEADS 16
#define HD 64
#define ROTD 32
#define EXPF 4
#define NXE 8388608L   // B*C*BINS*W
#define NTW 32         // w-columns per norm block

typedef unsigned short ushortT;
typedef short bf16x8 __attribute__((ext_vector_type(8)));
typedef float f32x4 __attribute__((ext_vector_type(4)));

__device__ __forceinline__ ushortT f2bf(float f) {
    unsigned int u = __float_as_uint(f);
    u = (u + 0x7FFF + ((u >> 16) & 1)) >> 16;
    return (ushortT)u;
}
__device__ __forceinline__ float bf2f(ushortT h) {
    return __uint_as_float(((unsigned int)h) << 16);
}
__device__ __forceinline__ unsigned int cvtpk(float lo, float hi) {
    unsigned int r;
    asm("v_cvt_pk_bf16_f32 %0, %1, %2" : "=v"(r) : "v"(lo), "v"(hi));
    return r;
}
__device__ __forceinline__ float geluf(float x) {
    return 0.5f * x * (1.f + erff(x * 0.70710678118654752f));
}
__device__ __forceinline__ void gl_lds16(const ushortT* g, ushortT* l) {
    __builtin_amdgcn_global_load_lds(
        (const __attribute__((address_space(1))) unsigned int*)g,
        (__attribute__((address_space(3))) unsigned int*)l, 16, 0, 0);
}

// ---------------- frame norm over BINS, transposed bf16 out [w][f] ----------------
__global__ __launch_bounds__(1024)
void normT_k(const float* __restrict__ X, const float* __restrict__ wgt,
             const float* __restrict__ bia, ushortT* __restrict__ YT)
{
    __shared__ float tile[NTW][BINS + 1];
    __shared__ float red0[32][NTW], red1[32][NTW];
    __shared__ float ms[NTW], is[NTW];
    const int bc = blockIdx.x >> 4;
    const int w0 = (blockIdx.x & 15) * NTW;
    const int tid = threadIdx.x;
    const int w  = tid & (NTW - 1);
    const int fy = tid >> 5;
    const float* Xb = X + (long)bc * BINS * WW + w0;
    float s = 0.f, s2 = 0.f;
    for (int f = fy; f < BINS; f += 32) {
        float v = Xb[(long)f * WW + w];
        s += v; s2 += v * v;
        tile[w][f] = v;
    }
    red0[fy][w] = s; red1[fy][w] = s2;
    __syncthreads();
    if (tid < NTW) {
        float ss = 0.f, qq = 0.f;
        #pragma unroll
        for (int j = 0; j < 32; ++j) { ss += red0[j][tid]; qq += red1[j][tid]; }
        float m = ss * (1.f / BINS);
        float var = qq * (1.f / BINS) - m * m;
        ms[tid] = m; is[tid] = rsqrtf(var + 1e-5f);
    }
    __syncthreads();
    const int w2 = tid >> 5;
    const int c  = tid & 31;
    float m = ms[w2], inv = is[w2];
    ushortT* Yb = YT + ((long)bc * WW + w0 + w2) * BINS;
    #pragma unroll
    for (int jj = 0; jj < 4; ++jj) {
        int f0 = jj * 256 + c * 8;
        union { ushortT h[8]; uint4 v; } r;
        #pragma unroll
        for (int e = 0; e < 8; ++e) {
            int f = f0 + e;
            float v = (tile[w2][f] - m) * inv * wgt[f] + bia[f];
            r.h[e] = f2bf(v);
        }
        *(uint4*)&Yb[f0] = r.v;
    }
}

// ---------------- RoPE tables ----------------
__global__ void rope_tab_k(const float* __restrict__ freqs,
                           float* __restrict__ cosT, float* __restrict__ sinT)
{
    int idx = blockIdx.x * 256 + threadIdx.x;
    if (idx >= WW * 16) return;
    int w = idx >> 4, i = idx & 15;
    float ang = (float)w * freqs[i];
    cosT[idx] = cosf(ang);
    sinT[idx] = sinf(ang);
}

// ---------------- MFMA flash attention ----------------
__global__ __launch_bounds__(256)
void mattn_k(const ushortT* __restrict__ rotT, const ushortT* __restrict__ yT,
             ushortT* __restrict__ oT)
{
    __shared__ ushortT Qs[64 * 64];
    __shared__ ushortT Ks[64 * 64];
    __shared__ ushortT Vs[64 * 72];
    __shared__ ushortT Ps[64 * 72];
    const int z = blockIdx.y;
    const int bc = z >> 4, h = z & 15;
    const int wq0 = blockIdx.x * 64;
    const int tid = threadIdx.x;
    const int wv = tid >> 6, l = tid & 63;
    const int lr = l & 15, lk = l >> 4;
    const long hbase = (long)bc * WW * 1024 + h * 64;

    #pragma unroll
    for (int p = 0; p < 2; ++p) {
        int r0 = p * 32 + wv * 8;
        int row = r0 + (l >> 3);
        int gs = (l & 7) ^ (row & 7);
        gl_lds16(rotT + hbase + (long)(wq0 + row) * 1024 + gs * 8, Qs + r0 * 64);
    }

    f32x4 oacc[4] = {};
    float mrow[4] = {-INFINITY, -INFINITY, -INFINITY, -INFINITY};
    float lrow[4] = {0.f, 0.f, 0.f, 0.f};

    for (int u0 = 0; u0 < WW; u0 += 64) {
        #pragma unroll
        for (int p = 0; p < 2; ++p) {
            int r0 = p * 32 + wv * 8;
            int row = r0 + (l >> 3);
            int gs = (l & 7) ^ (row & 7);
            gl_lds16(rotT + hbase + (long)(u0 + row) * 1024 + gs * 8, Ks + r0 * 64);
        }
        #pragma unroll
        for (int rep = 0; rep < 2; ++rep) {
            int ch = rep * 4 + wv;
            union { uint4 v; ushortT h8[8]; } tmp;
            tmp.v = *(const uint4*)(yT + hbase + (long)(u0 + l) * 1024 + ch * 8);
            #pragma unroll
            for (int j = 0; j < 8; ++j)
                Vs[(ch * 8 + j) * 72 + l] = tmp.h8[j];
        }
        __syncthreads();

        f32x4 sacc[4] = {};
        #pragma unroll
        for (int ko = 0; ko < 2; ++ko) {
            int ar = wv * 16 + lr;
            bf16x8 aq = *(const bf16x8*)&Qs[ar * 64 + (((ko * 4) + lk) ^ (ar & 7)) * 8];
            #pragma unroll
            for (int f = 0; f < 4; ++f) {
                int br = f * 16 + lr;
                bf16x8 bk = *(const bf16x8*)&Ks[br * 64 + (((ko * 4) + lk) ^ (br & 7)) * 8];
                sacc[f] = __builtin_amdgcn_mfma_f32_16x16x32_bf16(aq, bk, sacc[f], 0, 0, 0);
            }
        }

        #pragma unroll
        for (int rg = 0; rg < 4; ++rg) {
            float s0 = sacc[0][rg] * (1.f / 32.f);
            float s1 = sacc[1][rg] * (1.f / 32.f);
            float s2 = sacc[2][rg] * (1.f / 32.f);
            float s3 = sacc[3][rg] * (1.f / 32.f);
            float mx = fmaxf(fmaxf(s0, s1), fmaxf(s2, s3));
            mx = fmaxf(mx, __shfl_xor(mx, 1));
            mx = fmaxf(mx, __shfl_xor(mx, 2));
            mx = fmaxf(mx, __shfl_xor(mx, 4));
            mx = fmaxf(mx, __shfl_xor(mx, 8));
            float mnew = fmaxf(mrow[rg], mx);
            float al = __expf(mrow[rg] - mnew);
            float p0 = __expf(s0 - mnew), p1 = __expf(s1 - mnew);
            float p2 = __expf(s2 - mnew), p3 = __expf(s3 - mnew);
            float rs = p0 + p1 + p2 + p3;
            rs += __shfl_xor(rs, 1);
            rs += __shfl_xor(rs, 2);
            rs += __shfl_xor(rs, 4);
            rs += __shfl_xor(rs, 8);
            lrow[rg] = lrow[rg] * al + rs;
            mrow[rg] = mnew;
            oacc[0][rg] *= al; oacc[1][rg] *= al;
            oacc[2][rg] *= al; oacc[3][rg] *= al;
            int prow = wv * 16 + lk * 4 + rg;
            Ps[prow * 72 +  0 + lr] = f2bf(p0);
            Ps[prow * 72 + 16 + lr] = f2bf(p1);
            Ps[prow * 72 + 32 + lr] = f2bf(p2);
            Ps[prow * 72 + 48 + lr] = f2bf(p3);
        }
        asm volatile("s_waitcnt lgkmcnt(0)" ::: "memory");

        #pragma unroll
        for (int ko = 0; ko < 2; ++ko) {
            int ar = wv * 16 + lr;
            bf16x8 ap = *(const bf16x8*)&Ps[ar * 72 + ko * 32 + lk * 8];
            #pragma unroll
            for (int f = 0; f < 4; ++f) {
                bf16x8 bv = *(const bf16x8*)&Vs[(f * 16 + lr) * 72 + ko * 32 + lk * 8];
                oacc[f] = __builtin_amdgcn_mfma_f32_16x16x32_bf16(ap, bv, oacc[f], 0, 0, 0);
            }
        }
        __syncthreads();
    }

    #pragma unroll
    for (int rg = 0; rg < 4; ++rg) {
        float inv = 1.f / lrow[rg];
        int w = wq0 + wv * 16 + lk * 4 + rg;
        long b2 = (long)bc * WW * 1024 + (long)w * 1024 + h * 64;
        #pragma unroll
        for (int f = 0; f < 4; ++f)
            oT[b2 + f * 16 + lr] = f2bf(oacc[f][rg] * inv);
    }
}

// ================= quadrant-phased 256x256 GEMM, FUSED fp32->bf16 A-cast =========
// C[z][M][N] = A_f32[z%aMod][M][K] @ B_bf16[z][N][K]^T, BK=64, 8 waves.
// A: reg-fetch fp32 (p3, tile T+2) -> cvtpk -> ds_write (p1 of iter T commits
//    tile T+1 into the other buffer, retired at iter T-1 p4 lgkm+barrier).
// B: gl_lds halves as before (p2: T+1 qn1; p4: T+2 qn0).
// vmcnt(10) at p4 = B(T+1) drained, A(T+2) 8 loads + B(T+2)q0 2 in flight.
#define QPHASE(QM, QN, STAGES, VMW)                                          \
  {                                                                          \
    bf16x8 a0_[4], a1_[4], b0_[2], b1_[2];                                   \
    _Pragma("unroll")                                                        \
    for (int i = 0; i < 4; ++i) {                                            \
        int ra = wr * 128 + QM * 64 + i * 16 + lrow;                         \
        a0_[i] = *(const bf16x8*)&As[ra * 64 + ((lk    ) ^ (ra & 7)) * 8];   \
        a1_[i] = *(const bf16x8*)&As[ra * 64 + ((lk + 4) ^ (ra & 7)) * 8];   \
    }                                                                        \
    _Pragma("unroll")                                                        \
    for (int j = 0; j < 2; ++j) {                                            \
        int rb = wc * 64 + QN * 32 + j * 16 + lrow;                          \
        b0_[j] = *(const bf16x8*)&Bs[rb * 64 + ((lk    ) ^ (rb & 7)) * 8];   \
        b1_[j] = *(const bf16x8*)&Bs[rb * 64 + ((lk + 4) ^ (rb & 7)) * 8];   \
    }                                                                        \
    STAGES;                                                                  \
    VMW;                                                                     \
    asm volatile("s_waitcnt lgkmcnt(0)" ::: "memory");                       \
    __builtin_amdgcn_s_barrier();                                            \
    __builtin_amdgcn_s_setprio(1);                                           \
    _Pragma("unroll")                                                        \
    for (int i = 0; i < 4; ++i)                                              \
        _Pragma("unroll")                                                    \
        for (int j = 0; j < 2; ++j)                                          \
            acc[QM * 4 + i][QN * 2 + j] =                                    \
                __builtin_amdgcn_mfma_f32_16x16x32_bf16(                     \
                    a0_[i], b0_[j], acc[QM * 4 + i][QN * 2 + j], 0, 0, 0);   \
    _Pragma("unroll")                                                        \
    for (int i = 0; i < 4; ++i)                                              \
        _Pragma("unroll")                                                    \
        for (int j = 0; j < 2; ++j)                                          \
            acc[QM * 4 + i][QN * 2 + j] =                                    \
                __builtin_amdgcn_mfma_f32_16x16x32_bf16(                     \
                    a1_[i], b1_[j], acc[QM * 4 + i][QN * 2 + j], 0, 0, 0);   \
    __builtin_amdgcn_s_setprio(0);                                           \
  }

template<bool HASRES, bool GELUF, bool TRANSOUT>
__global__ __launch_bounds__(512)
void gemm8f_k(const float* __restrict__ A, long sA, int aMod,
              const ushortT* __restrict__ B, long sB,
              void* __restrict__ Cp, long sC,
              const float* __restrict__ R, long sR,
              int M, int N, int K, int gx, int gy)
{
    __shared__ ushortT smem[65536];   // 128 KiB: buf d at d*32768 (A | B+16384)
    const int nwg = gridDim.x;
    const int bid = blockIdx.x;
    const int lid = (bid & 7) * (nwg >> 3) + (bid >> 3);
    const int x = lid % gx;
    const int y = (lid / gx) % gy;
    const int z = lid / (gx * gy);
    const float*   Ab = A + (long)(z % aMod) * sA + (long)y * 256 * K;
    const ushortT* Bb = B + (long)z * sB + (long)x * 256 * K;
    const int tid = threadIdx.x;
    const int wv = tid >> 6, l = tid & 63;
    const int lrow = l & 15, lk = l >> 4;
    const int wr = wv >> 2, wc = wv & 3;
    f32x4 acc[8][4] = {};
    float4 rA[8];
    const int NT = K >> 6;

    auto fetchA = [&](int T) {               // 8 dwordx4 fp32 -> regs
        const int k0 = T << 6;
        #pragma unroll
        for (int c = 0; c < 4; ++c) {
            int idx = tid + c * 512;
            int row = idx >> 3, grp = idx & 7;
            const float* src = Ab + (long)row * K + k0 + grp * 8;
            rA[c * 2]     = *(const float4*)src;
            rA[c * 2 + 1] = *(const float4*)(src + 4);
        }
    };
    auto commitA = [&](int T) {              // cvtpk -> 4 ds_write_b128
        ushortT* D = smem + (T & 1) * 32768;
        #pragma unroll
        for (int c = 0; c < 4; ++c) {
            int idx = tid + c * 512;
            int row = idx >> 3, grp = idx & 7;
            uint4 v;
            v.x = cvtpk(rA[c * 2].x,     rA[c * 2].y);
            v.y = cvtpk(rA[c * 2].z,     rA[c * 2].w);
            v.z = cvtpk(rA[c * 2 + 1].x, rA[c * 2 + 1].y);
            v.w = cvtpk(rA[c * 2 + 1].z, rA[c * 2 + 1].w);
            *(uint4*)&D[row * 64 + ((grp ^ (row & 7)) << 3)] = v;
        }
    };
    auto stageBh = [&](int T, int qn) {      // 2 gl_lds
        ushortT* D = smem + (T & 1) * 32768 + 16384;
        const int k0 = T << 6;
        #pragma unroll
        for (int t = 0; t < 2; ++t) {
            int r0 = wv * 16 + t * 8;
            int gr0 = ((r0 >> 5) << 6) + qn * 32 + (r0 & 31);
            int gr = gr0 + (l >> 3);
            int gs = (l & 7) ^ (gr & 7);
            gl_lds16(Bb + (long)gr * K + k0 + gs * 8, D + gr0 * 64);
        }
    };

    // prologue: A(0) fetched+committed; B(0) both halves; A(1) regs; B(1) qn0.
    fetchA(0);
    commitA(0);
    stageBh(0, 0); stageBh(0, 1);
    if (NT > 1) {
        fetchA(1);
        stageBh(1, 0);
        asm volatile("s_waitcnt vmcnt(10) lgkmcnt(0)" ::: "memory");
    } else {
        asm volatile("s_waitcnt vmcnt(0) lgkmcnt(0)" ::: "memory");
    }
    __builtin_amdgcn_s_barrier();

    for (int T = 0; T < NT; ++T) {
        const ushortT* As = smem + (T & 1) * 32768;
        const ushortT* Bs = As + 16384;
        const bool s1 = (T + 1 < NT), s2 = (T + 2 < NT);
        QPHASE(0, 0, if (s1) commitA(T + 1), );
        QPHASE(0, 1, if (s1) stageBh(T + 1, 1), );
        QPHASE(1, 0, if (s2) fetchA(T + 2), );
        QPHASE(1, 1, if (s2) stageBh(T + 2, 0),
               if (s2) { asm volatile("s_waitcnt vmcnt(10)" ::: "memory"); }
               else    { asm volatile("s_waitcnt vmcnt(0)" ::: "memory"); });
    }

    const int m0g = y * 256 + wr * 128, n0g = x * 256 + wc * 64;
    if (!TRANSOUT) {
        float* Cf = (float*)Cp + (long)z * sC;
        #pragma unroll
        for (int ip = 0; ip < 8; ++ip)
            #pragma unroll
            for (int j = 0; j < 4; ++j)
                #pragma unroll
                for (int rg = 0; rg < 4; ++rg) {
                    long m = m0g + ip * 16 + lk * 4 + rg;
                    long n = n0g + j * 16 + lrow;
                    float v = acc[ip][j][rg];
                    if (GELUF) v = geluf(v);
                    if (HASRES) v += R[(long)z * sR + m * N + n];
                    Cf[m * N + n] = v;
                }
    } else {
        __syncthreads();
        ushortT* Ts = smem + wv * 4096;
        ushortT* CT = (ushortT*)Cp + (long)z * sC;
        #pragma unroll
        for (int s = 0; s < 2; ++s) {
            #pragma unroll
            for (int i2 = 0; i2 < 4; ++i2)
                #pragma unroll
                for (int j = 0; j < 4; ++j)
                    #pragma unroll
                    for (int rg = 0; rg < 4; ++rg) {
                        int ml = i2 * 16 + lk * 4 + rg;
                        int nl = j * 16 + lrow;
                        float v = acc[s * 4 + i2][j][rg];
                        if (GELUF) v = geluf(v);
                        Ts[nl * 64 + (((ml >> 3) ^ (nl & 7)) << 3) + (ml & 7)] = f2bf(v);
                    }
            #pragma unroll
            for (int p = 0; p < 8; ++p) {
                int nl = p * 8 + (l >> 3), mc = l & 7;
                uint4 d = *(const uint4*)&Ts[nl * 64 + ((mc ^ (nl & 7)) << 3)];
                *(uint4*)&CT[(long)(n0g + nl) * M + m0g + s * 64 + mc * 8] = d;
            }
        }
    }
}

// ---------------- pipelined GEMM, 3-slot, FUSED fp32->bf16 A-cast (lin2) ----------
// Per iter T: commitA(T+1) [slot retired 2 barriers ago]; fetchA(T+2); stageB(T+2);
// compute(T); vmcnt(8) [B(T+1) drained, A(T+2)+B(T+2) fly] + lgkmcnt(0); barrier.
template<bool HASRES, bool GELUF, bool TRANSOUT>
__global__ __launch_bounds__(512)
void pgemmf_k(const float* __restrict__ A, long sA, int aMod,
              const ushortT* __restrict__ B, long sB,
              void* __restrict__ Cp, long sC,
              const float* __restrict__ R, long sR,
              int M, int N, int K, int gx, int gy)
{
    __shared__ ushortT smem[3 * 24576];
    const int nwg = gridDim.x;
    const int bid = blockIdx.x;
    const int lid = (bid & 7) * (nwg >> 3) + (bid >> 3);
    const int x = lid % gx;
    const int y = (lid / gx) % gy;
    const int z = lid / (gx * gy);
    const float*   Ab = A + (long)(z % aMod) * sA + (long)y * 128 * K;
    const ushortT* Bb = B + (long)z * sB + (long)x * 256 * K;
    const int tid = threadIdx.x;
    const int wv = tid >> 6, l = tid & 63;
    const int lrow = l & 15, lk = l >> 4;
    const int mb = (wv >> 2) * 64;
    const int nb = (wv & 3) * 64;
    f32x4 acc[4][4] = {};
    float4 rA[4];
    const int NT = K >> 6;

    auto fetchA = [&](int T) {               // 4 dwordx4 fp32
        const int k0 = T << 6;
        #pragma unroll
        for (int c = 0; c < 2; ++c) {
            int idx = tid + c * 512;
            int row = idx >> 3, grp = idx & 7;
            const float* src = Ab + (long)row * K + k0 + grp * 8;
            rA[c * 2]     = *(const float4*)src;
            rA[c * 2 + 1] = *(const float4*)(src + 4);
        }
    };
    auto commitA = [&](int T) {              // 2 ds_write_b128
        ushortT* As = smem + (T % 3) * 24576;
        #pragma unroll
        for (int c = 0; c < 2; ++c) {
            int idx = tid + c * 512;
            int row = idx >> 3, grp = idx & 7;
            uint4 v;
            v.x = cvtpk(rA[c * 2].x,     rA[c * 2].y);
            v.y = cvtpk(rA[c * 2].z,     rA[c * 2].w);
            v.z = cvtpk(rA[c * 2 + 1].x, rA[c * 2 + 1].y);
            v.w = cvtpk(rA[c * 2 + 1].z, rA[c * 2 + 1].w);
            *(uint4*)&As[row * 64 + ((grp ^ (row & 7)) << 3)] = v;
        }
    };
    auto stageB = [&](int T) {               // 4 gl_lds
        ushortT* Bs = smem + (T % 3) * 24576 + 8192;
        const int k0 = T << 6;
        #pragma unroll
        for (int t = 0; t < 4; ++t) {
            int r0 = wv * 32 + t * 8;
            int row = r0 + (l >> 3);
            int gs = (l & 7) ^ (row & 7);
            gl_lds16(Bb + (long)row * K + k0 + gs * 8, Bs + r0 * 64);
        }
    };
    auto compute = [&](int T) {
        const ushortT* S = smem + (T % 3) * 24576;
        const ushortT* As = S;
        const ushortT* Bs = S + 8192;
        #pragma unroll
        for (int ko = 0; ko < 2; ++ko) {
            bf16x8 af[4], bg[4];
            #pragma unroll
            for (int i = 0; i < 4; ++i) {
                int ra = mb + i * 16 + lrow;
                af[i] = *(const bf16x8*)&As[ra * 64 + ((lk + ko * 4) ^ (ra & 7)) * 8];
                int rb = nb + i * 16 + lrow;
                bg[i] = *(const bf16x8*)&Bs[rb * 64 + ((lk + ko * 4) ^ (rb & 7)) * 8];
            }
            #pragma unroll
            for (int i = 0; i < 4; ++i)
                #pragma unroll
                for (int j = 0; j < 4; ++j)
                    acc[i][j] = __builtin_amdgcn_mfma_f32_16x16x32_bf16(
                        af[i], bg[j], acc[i][j], 0, 0, 0);
        }
    };

    fetchA(0); commitA(0); stageB(0);
    if (NT > 1) {
        fetchA(1); stageB(1);
        asm volatile("s_waitcnt vmcnt(8) lgkmcnt(0)" ::: "memory");
    } else {
        asm volatile("s_waitcnt vmcnt(0) lgkmcnt(0)" ::: "memory");
    }
    __builtin_amdgcn_s_barrier();

    for (int T = 0; T < NT; ++T) {
        const bool s1 = (T + 1 < NT), s2 = (T + 2 < NT);
        if (s1) commitA(T + 1);
        if (s2) { fetchA(T + 2); stageB(T + 2); }
        compute(T);
        if (s1) {
            if (s2) asm volatile("s_waitcnt vmcnt(8) lgkmcnt(0)" ::: "memory");
            else    asm volatile("s_waitcnt vmcnt(0) lgkmcnt(0)" ::: "memory");
            __builtin_amdgcn_s_barrier();
        }
    }

    const int m0g = y * 128 + mb, n0g = x * 256 + nb;
    if (!TRANSOUT) {
        float* Cf = (float*)Cp + (long)z * sC;
        #pragma unroll
        for (int i = 0; i < 4; ++i)
            #pragma unroll
            for (int j = 0; j < 4; ++j)
                #pragma unroll
                for (int rg = 0; rg < 4; ++rg) {
                    long m = m0g + i * 16 + lk * 4 + rg;
                    long n = n0g + j * 16 + lrow;
                    float v = acc[i][j][rg];
                    if (GELUF) v = geluf(v);
                    if (HASRES) v += R[(long)z * sR + m * N + n];
                    Cf[m * N + n] = v;
                }
    } else {
        __syncthreads();
        ushortT* Ts = smem + wv * 4096;
        #pragma unroll
        for (int i = 0; i < 4; ++i)
            #pragma unroll
            for (int j = 0; j < 4; ++j)
                #pragma unroll
                for (int rg = 0; rg < 4; ++rg) {
                    int ml = i * 16 + lk * 4 + rg;
                    int nl = j * 16 + lrow;
                    float v = acc[i][j][rg];
                    if (GELUF) v = geluf(v);
                    Ts[nl * 64 + (((ml >> 3) ^ (nl & 7)) << 3) + (ml & 7)] = f2bf(v);
                }
        __syncthreads();
        ushortT* CT = (ushortT*)Cp + (long)z * sC;
        #pragma unroll
        for (int p = 0; p < 8; ++p) {
            int nl = p * 8 + (l >> 3), mc = l & 7;
            uint4 d = *(const uint4*)&Ts[nl * 64 + ((mc ^ (nl & 7)) << 3)];
            *(uint4*)&CT[(long)(n0g + nl) * M + m0g + mc * 8] = d;
        }
    }
}

// ---------------- fused-cast MFMA GEMM, simple 2-barrier (qproj/outproj) ----------------
template<bool HASRES, bool GELUF, bool TRANSOUT, bool ROPE>
__global__ __launch_bounds__(256)
void fgemm_k(const float* __restrict__ A, long sA, int aMod,
             const ushortT* __restrict__ B, long sB,
             void* __restrict__ Cp, long sC,
             const float* __restrict__ R, long sR,
             ushortT* __restrict__ Crot,
             const float* __restrict__ cosT, const float* __restrict__ sinT,
             int M, int N, int K, int gx, int gy)
{
    __shared__ ushortT smem[2 * 8192];
    ushortT* As = smem;
    ushortT* Bs = smem + 8192;
    const int nwg = gridDim.x;
    const int bid = blockIdx.x;
    const int lid = (bid & 7) * (nwg >> 3) + (bid >> 3);
    const int x = lid % gx;
    const int y = (lid / gx) % gy;
    const int z = lid / (gx * gy);
    const float*   Ab = A + (long)(z % aMod) * sA + (long)y * 128 * K;
    const ushortT* Bb = B + (long)z * sB + (long)x * 128 * K;
    const int tid = threadIdx.x;
    const int wv = tid >> 6, l = tid & 63;
    const int lrow = l & 15, lk = l >> 4;
    const int mb = (wv >> 1) * 64, nb = (wv & 1) * 64;
    const int arow = tid >> 3, agrp = tid & 7;
    f32x4 acc[4][4] = {};
    float4 a0[4], a1[4];
    const int NT = K >> 6;

    auto fetchA = [&](int k0) {
        #pragma unroll
        for (int c = 0; c < 4; ++c) {
            const float* src = Ab + (long)(arow + c * 32) * K + k0 + agrp * 8;
            a0[c] = *(const float4*)src;
            a1[c] = *(const float4*)(src + 4);
        }
    };
    auto commitA = [&]() {
        #pragma unroll
        for (int c = 0; c < 4; ++c) {
            int row = arow + c * 32;
            uint4 v;
            v.x = cvtpk(a0[c].x, a0[c].y);
            v.y = cvtpk(a0[c].z, a0[c].w);
            v.z = cvtpk(a1[c].x, a1[c].y);
            v.w = cvtpk(a1[c].z, a1[c].w);
            *(uint4*)&As[row * 64 + ((agrp ^ (row & 7)) << 3)] = v;
        }
    };
    auto stageB = [&](int k0) {
        #pragma unroll
        for (int t = 0; t < 4; ++t) {
            int r0 = wv * 32 + t * 8;
            int row = r0 + (l >> 3);
            int gs = (l & 7) ^ (row & 7);
            gl_lds16(Bb + (long)row * K + k0 + gs * 8, Bs + r0 * 64);
        }
    };
    auto compute = [&]() {
        #pragma unroll
        for (int ko = 0; ko < 2; ++ko) {
            bf16x8 af[4], bg[4];
            #pragma unroll
            for (int i = 0; i < 4; ++i) {
                int ra = mb + i * 16 + lrow;
                af[i] = *(const bf16x8*)&As[ra * 64 + ((lk + ko * 4) ^ (ra & 7)) * 8];
                int rb = nb + i * 16 + lrow;
                bg[i] = *(const bf16x8*)&Bs[rb * 64 + ((lk + ko * 4) ^ (rb & 7)) * 8];
            }
            #pragma unroll
            for (int i = 0; i < 4; ++i)
                #pragma unroll
                for (int j = 0; j < 4; ++j)
                    acc[i][j] = __builtin_amdgcn_mfma_f32_16x16x32_bf16(
                        af[i], bg[j], acc[i][j], 0, 0, 0);
        }
    };

    fetchA(0);
    for (int t = 0; t < NT; ++t) {
        if (t > 0) __syncthreads();
        stageB(t << 6);
        commitA();
        if (t + 1 < NT) fetchA((t + 1) << 6);
        __syncthreads();
        compute();
    }

    const int m0g = y * 128 + mb, n0g = x * 128 + nb;
    if (!TRANSOUT) {
        float* Cf = (float*)Cp + (long)z * sC;
        #pragma unroll
        for (int i = 0; i < 4; ++i)
            #pragma unroll
            for (int j = 0; j < 4; ++j)
                #pragma unroll
                for (int rg = 0; rg < 4; ++rg) {
                    long m = m0g + i * 16 + lk * 4 + rg;
                    long n = n0g + j * 16 + lrow;
                    float v = acc[i][j][rg];
                    if (GELUF) v = geluf(v);
                    if (HASRES) v += R[(long)z * sR + m * N + n];
                    Cf[m * N + n] = v;
                }
    } else {
        ushortT* Ts = smem + wv * 4096;
        __syncthreads();
        #pragma unroll
        for (int i = 0; i < 4; ++i)
            #pragma unroll
            for (int j = 0; j < 4; ++j)
                #pragma unroll
                for (int rg = 0; rg < 4; ++rg) {
                    int ml = i * 16 + lk * 4 + rg;
                    int nl = j * 16 + lrow;
                    float v = acc[i][j][rg];
                    if (GELUF) v = geluf(v);
                    Ts[nl * 64 + (((ml >> 3) ^ (nl & 7)) << 3) + (ml & 7)] = f2bf(v);
                }
        __syncthreads();
        ushortT* CT = (ushortT*)Cp + (long)z * sC;
        #pragma unroll
        for (int p = 0; p < 8; ++p) {
            int nl = p * 8 + (l >> 3), mc = l & 7;
            uint4 d = *(const uint4*)&Ts[nl * 64 + ((mc ^ (nl & 7)) << 3)];
            int wg = n0g + nl;
            int g0 = m0g + mc * 8;
            *(uint4*)&CT[(long)wg * M + g0] = d;
            if (ROPE) {
                ushortT* RT = Crot + (long)z * sC;
                int d0 = g0 & 63;
                if (d0 >= ROTD) {
                    *(uint4*)&RT[(long)wg * M + g0] = d;
                } else {
                    union { uint4 v; ushortT h8[8]; } in, ov;
                    in.v = d;
                    #pragma unroll
                    for (int j = 0; j < 8; j += 2) {
                        int i2 = (d0 + j) >> 1;
                        float cc = cosT[wg * 16 + i2], ss = sinT[wg * 16 + i2];
                        float a = bf2f(in.h8[j]), b = bf2f(in.h8[j + 1]);
                        ov.h8[j]     = f2bf(a * cc - b * ss);
                        ov.h8[j + 1] = f2bf(b * cc + a * ss);
                    }
                    *(uint4*)&RT[(long)wg * M + g0] = ov.v;
                }
            }
        }
    }
}

extern "C" void kernel_launch(void* const* d_in, const int* in_sizes, int n_in,
                              void* d_out, int out_size, void* d_ws, size_t ws_size,
                              hipStream_t stream)
{
    const float* x    = (const float*)d_in[0];
    const float* n1w  = (const float*)d_in[1];
    const float* n1b  = (const float*)d_in[2];
    const float* freqs= (const float*)d_in[3];
    const float* qw   = (const float*)d_in[4];
    const float* ow   = (const float*)d_in[5];
    const float* n2w  = (const float*)d_in[6];
    const float* n2b  = (const float*)d_in[7];
    const float* l1w  = (const float*)d_in[8];
    const float* l2w  = (const float*)d_in[9];
    float* out = (float*)d_out;
    char* wsb  = (char*)d_ws;
    const long MB = 1L << 20;

    ushortT* znT  = (ushortT*)(wsb +   0 * MB);   // 16MB (dead after qproj)
    ushortT* yT   = (ushortT*)(wsb +  16 * MB);   // 16MB (dead after attn)
    ushortT* rotT = (ushortT*)(wsb +  32 * MB);   // 16MB (dead after attn)
    ushortT* CfT  = (ushortT*)(wsb +  48 * MB);   // 16MB (dead after outproj)
    ushortT* zn2T = (ushortT*)(wsb +  64 * MB);   // 16MB
    ushortT* h1T  = (ushortT*)(wsb +  80 * MB);   // 64MB
    float*   cosT = (float*)  (wsb + 144 * MB);
    float*   sinT = cosT + WW * 16;

    rope_tab_k<<<32, 256, 0, stream>>>(freqs, cosT, sinT);

    // norm1: x -> znT (bf16 [w][f])
    normT_k<<<BB * CCH * 16, 1024, 0, stream>>>(x, n1w, n1b, znT);

    // qproj + fused RoPE: yT (raw) and rotT (rotated), both [bc][w][g]
    fgemm_k<false, false, true, true><<<512, 256, 0, stream>>>(
        qw,  (long)BINS * BINS, CCH,
        znT, (long)WW * BINS,
        yT,  (long)WW * BINS,
        nullptr, 0,
        rotT, cosT, sinT,
        BINS, WW, BINS, 4, 8);

    // MFMA flash attention -> CfT [bc][w][g]
    mattn_k<<<dim3(8, 256), 256, 0, stream>>>(rotT, yT, CfT);

    // outproj + residual: out = x + ow[c] @ CfT^T
    fgemm_k<true, false, false, false><<<512, 256, 0, stream>>>(
        ow,  (long)BINS * BINS, CCH,
        CfT, (long)WW * BINS,
        out, (long)BINS * WW,
        x,   (long)BINS * WW,
        nullptr, nullptr, nullptr,
        BINS, WW, BINS, 4, 8);

    // norm2: out -> zn2T (bf16 [w][f])
    normT_k<<<BB * CCH * 16, 1024, 0, stream>>>(out, n2w, n2b, zn2T);

    // lin1 + GELU (quadrant-phased 256x256, fused fp32 A-cast): h1T [w][4096]
    gemm8f_k<false, true, true><<<512, 512, 0, stream>>>(
        l1w,  (long)BINS * EXPF * BINS, CCH,
        zn2T, (long)WW * BINS,
        h1T,  (long)WW * BINS * EXPF,
        nullptr, 0,
        BINS * EXPF, WW, BINS, 2, 16);

    // lin2 + residual (pipelined 3-slot, fused fp32 A-cast, in-place on out)
    pgemmf_k<true, false, false><<<256, 512, 0, stream>>>(
        l2w, (long)BINS * BINS * EXPF, CCH,
        h1T, (long)WW * BINS * EXPF,
        out, (long)BINS * WW,
        out, (long)BINS * WW,
        BINS, WW, BINS * EXPF, 2, 8);
}

// Round 15
// 428.759 us; speedup vs baseline: 1.0889x; 1.0889x over previous
//
#include <hip/hip_runtime.h>
#include <math.h>

#define BB 2
#define CCH 8
#define BINS 1024
#define WW 512
#define HEADS 16
#define HD 64
#define ROTD 32
#define EXPF 4
#define NXE 8388608L   // B*C*BINS*W
#define NTW 32         // w-columns per norm block

typedef unsigned short ushortT;
typedef short bf16x8 __attribute__((ext_vector_type(8)));
typedef float f32x4 __attribute__((ext_vector_type(4)));

__device__ __forceinline__ ushortT f2bf(float f) {
    unsigned int u = __float_as_uint(f);
    u = (u + 0x7FFF + ((u >> 16) & 1)) >> 16;
    return (ushortT)u;
}
__device__ __forceinline__ float bf2f(ushortT h) {
    return __uint_as_float(((unsigned int)h) << 16);
}
__device__ __forceinline__ unsigned int cvtpk(float lo, float hi) {
    unsigned int r;
    asm("v_cvt_pk_bf16_f32 %0, %1, %2" : "=v"(r) : "v"(lo), "v"(hi));
    return r;
}
__device__ __forceinline__ float geluf(float x) {
    return 0.5f * x * (1.f + erff(x * 0.70710678118654752f));
}
__device__ __forceinline__ void gl_lds16(const ushortT* g, ushortT* l) {
    __builtin_amdgcn_global_load_lds(
        (const __attribute__((address_space(1))) unsigned int*)g,
        (__attribute__((address_space(3))) unsigned int*)l, 16, 0, 0);
}

// ---------------- weight cast f32 -> bf16 ----------------
__global__ __launch_bounds__(256)
void wcast_k(const float* __restrict__ s, ushortT* __restrict__ d, long n)
{
    long i = ((long)blockIdx.x * 256 + threadIdx.x) * 8;
    if (i >= n) return;
    float4 a = *(const float4*)&s[i];
    float4 b = *(const float4*)&s[i + 4];
    uint4 v;
    v.x = cvtpk(a.x, a.y); v.y = cvtpk(a.z, a.w);
    v.z = cvtpk(b.x, b.y); v.w = cvtpk(b.z, b.w);
    *(uint4*)&d[i] = v;
}

// ---------------- frame norm over BINS, transposed bf16 out [w][f] ----------------
__global__ __launch_bounds__(1024)
void normT_k(const float* __restrict__ X, const float* __restrict__ wgt,
             const float* __restrict__ bia, ushortT* __restrict__ YT)
{
    __shared__ float tile[NTW][BINS + 1];
    __shared__ float red0[32][NTW], red1[32][NTW];
    __shared__ float ms[NTW], is[NTW];
    const int bc = blockIdx.x >> 4;
    const int w0 = (blockIdx.x & 15) * NTW;
    const int tid = threadIdx.x;
    const int w  = tid & (NTW - 1);
    const int fy = tid >> 5;
    const float* Xb = X + (long)bc * BINS * WW + w0;
    float s = 0.f, s2 = 0.f;
    for (int f = fy; f < BINS; f += 32) {
        float v = Xb[(long)f * WW + w];
        s += v; s2 += v * v;
        tile[w][f] = v;
    }
    red0[fy][w] = s; red1[fy][w] = s2;
    __syncthreads();
    if (tid < NTW) {
        float ss = 0.f, qq = 0.f;
        #pragma unroll
        for (int j = 0; j < 32; ++j) { ss += red0[j][tid]; qq += red1[j][tid]; }
        float m = ss * (1.f / BINS);
        float var = qq * (1.f / BINS) - m * m;
        ms[tid] = m; is[tid] = rsqrtf(var + 1e-5f);
    }
    __syncthreads();
    const int w2 = tid >> 5;
    const int c  = tid & 31;
    float m = ms[w2], inv = is[w2];
    ushortT* Yb = YT + ((long)bc * WW + w0 + w2) * BINS;
    #pragma unroll
    for (int jj = 0; jj < 4; ++jj) {
        int f0 = jj * 256 + c * 8;
        union { ushortT h[8]; uint4 v; } r;
        #pragma unroll
        for (int e = 0; e < 8; ++e) {
            int f = f0 + e;
            float v = (tile[w2][f] - m) * inv * wgt[f] + bia[f];
            r.h[e] = f2bf(v);
        }
        *(uint4*)&Yb[f0] = r.v;
    }
}

// ---------------- RoPE tables ----------------
__global__ void rope_tab_k(const float* __restrict__ freqs,
                           float* __restrict__ cosT, float* __restrict__ sinT)
{
    int idx = blockIdx.x * 256 + threadIdx.x;
    if (idx >= WW * 16) return;
    int w = idx >> 4, i = idx & 15;
    float ang = (float)w * freqs[i];
    cosT[idx] = cosf(ang);
    sinT[idx] = sinf(ang);
}

// ---------------- MFMA flash attention ----------------
__global__ __launch_bounds__(256)
void mattn_k(const ushortT* __restrict__ rotT, const ushortT* __restrict__ yT,
             ushortT* __restrict__ oT)
{
    __shared__ ushortT Qs[64 * 64];
    __shared__ ushortT Ks[64 * 64];
    __shared__ ushortT Vs[64 * 72];
    __shared__ ushortT Ps[64 * 72];
    const int z = blockIdx.y;
    const int bc = z >> 4, h = z & 15;
    const int wq0 = blockIdx.x * 64;
    const int tid = threadIdx.x;
    const int wv = tid >> 6, l = tid & 63;
    const int lr = l & 15, lk = l >> 4;
    const long hbase = (long)bc * WW * 1024 + h * 64;

    #pragma unroll
    for (int p = 0; p < 2; ++p) {
        int r0 = p * 32 + wv * 8;
        int row = r0 + (l >> 3);
        int gs = (l & 7) ^ (row & 7);
        gl_lds16(rotT + hbase + (long)(wq0 + row) * 1024 + gs * 8, Qs + r0 * 64);
    }

    f32x4 oacc[4] = {};
    float mrow[4] = {-INFINITY, -INFINITY, -INFINITY, -INFINITY};
    float lrow[4] = {0.f, 0.f, 0.f, 0.f};

    for (int u0 = 0; u0 < WW; u0 += 64) {
        #pragma unroll
        for (int p = 0; p < 2; ++p) {
            int r0 = p * 32 + wv * 8;
            int row = r0 + (l >> 3);
            int gs = (l & 7) ^ (row & 7);
            gl_lds16(rotT + hbase + (long)(u0 + row) * 1024 + gs * 8, Ks + r0 * 64);
        }
        #pragma unroll
        for (int rep = 0; rep < 2; ++rep) {
            int ch = rep * 4 + wv;
            union { uint4 v; ushortT h8[8]; } tmp;
            tmp.v = *(const uint4*)(yT + hbase + (long)(u0 + l) * 1024 + ch * 8);
            #pragma unroll
            for (int j = 0; j < 8; ++j)
                Vs[(ch * 8 + j) * 72 + l] = tmp.h8[j];
        }
        __syncthreads();

        f32x4 sacc[4] = {};
        #pragma unroll
        for (int ko = 0; ko < 2; ++ko) {
            int ar = wv * 16 + lr;
            bf16x8 aq = *(const bf16x8*)&Qs[ar * 64 + (((ko * 4) + lk) ^ (ar & 7)) * 8];
            #pragma unroll
            for (int f = 0; f < 4; ++f) {
                int br = f * 16 + lr;
                bf16x8 bk = *(const bf16x8*)&Ks[br * 64 + (((ko * 4) + lk) ^ (br & 7)) * 8];
                sacc[f] = __builtin_amdgcn_mfma_f32_16x16x32_bf16(aq, bk, sacc[f], 0, 0, 0);
            }
        }

        #pragma unroll
        for (int rg = 0; rg < 4; ++rg) {
            float s0 = sacc[0][rg] * (1.f / 32.f);
            float s1 = sacc[1][rg] * (1.f / 32.f);
            float s2 = sacc[2][rg] * (1.f / 32.f);
            float s3 = sacc[3][rg] * (1.f / 32.f);
            float mx = fmaxf(fmaxf(s0, s1), fmaxf(s2, s3));
            mx = fmaxf(mx, __shfl_xor(mx, 1));
            mx = fmaxf(mx, __shfl_xor(mx, 2));
            mx = fmaxf(mx, __shfl_xor(mx, 4));
            mx = fmaxf(mx, __shfl_xor(mx, 8));
            float mnew = fmaxf(mrow[rg], mx);
            float al = __expf(mrow[rg] - mnew);
            float p0 = __expf(s0 - mnew), p1 = __expf(s1 - mnew);
            float p2 = __expf(s2 - mnew), p3 = __expf(s3 - mnew);
            float rs = p0 + p1 + p2 + p3;
            rs += __shfl_xor(rs, 1);
            rs += __shfl_xor(rs, 2);
            rs += __shfl_xor(rs, 4);
            rs += __shfl_xor(rs, 8);
            lrow[rg] = lrow[rg] * al + rs;
            mrow[rg] = mnew;
            oacc[0][rg] *= al; oacc[1][rg] *= al;
            oacc[2][rg] *= al; oacc[3][rg] *= al;
            int prow = wv * 16 + lk * 4 + rg;
            Ps[prow * 72 +  0 + lr] = f2bf(p0);
            Ps[prow * 72 + 16 + lr] = f2bf(p1);
            Ps[prow * 72 + 32 + lr] = f2bf(p2);
            Ps[prow * 72 + 48 + lr] = f2bf(p3);
        }
        asm volatile("s_waitcnt lgkmcnt(0)" ::: "memory");

        #pragma unroll
        for (int ko = 0; ko < 2; ++ko) {
            int ar = wv * 16 + lr;
            bf16x8 ap = *(const bf16x8*)&Ps[ar * 72 + ko * 32 + lk * 8];
            #pragma unroll
            for (int f = 0; f < 4; ++f) {
                bf16x8 bv = *(const bf16x8*)&Vs[(f * 16 + lr) * 72 + ko * 32 + lk * 8];
                oacc[f] = __builtin_amdgcn_mfma_f32_16x16x32_bf16(ap, bv, oacc[f], 0, 0, 0);
            }
        }
        __syncthreads();
    }

    #pragma unroll
    for (int rg = 0; rg < 4; ++rg) {
        float inv = 1.f / lrow[rg];
        int w = wq0 + wv * 16 + lk * 4 + rg;
        long b2 = (long)bc * WW * 1024 + (long)w * 1024 + h * 64;
        #pragma unroll
        for (int f = 0; f < 4; ++f)
            oT[b2 + f * 16 + lr] = f2bf(oacc[f][rg] * inv);
    }
}

// ================= quadrant-phased 256x256 GEMM (lin1, bf16 A) =================
#define QPHASE(QM, QN, STAGES, VMW)                                          \
  {                                                                          \
    bf16x8 a0_[4], a1_[4], b0_[2], b1_[2];                                   \
    _Pragma("unroll")                                                        \
    for (int i = 0; i < 4; ++i) {                                            \
        int ra = wr * 128 + QM * 64 + i * 16 + lrow;                         \
        a0_[i] = *(const bf16x8*)&As[ra * 64 + ((lk    ) ^ (ra & 7)) * 8];   \
        a1_[i] = *(const bf16x8*)&As[ra * 64 + ((lk + 4) ^ (ra & 7)) * 8];   \
    }                                                                        \
    _Pragma("unroll")                                                        \
    for (int j = 0; j < 2; ++j) {                                            \
        int rb = wc * 64 + QN * 32 + j * 16 + lrow;                          \
        b0_[j] = *(const bf16x8*)&Bs[rb * 64 + ((lk    ) ^ (rb & 7)) * 8];   \
        b1_[j] = *(const bf16x8*)&Bs[rb * 64 + ((lk + 4) ^ (rb & 7)) * 8];   \
    }                                                                        \
    STAGES;                                                                  \
    VMW;                                                                     \
    asm volatile("s_waitcnt lgkmcnt(0)" ::: "memory");                       \
    __builtin_amdgcn_s_barrier();                                            \
    __builtin_amdgcn_s_setprio(1);                                           \
    _Pragma("unroll")                                                        \
    for (int i = 0; i < 4; ++i)                                              \
        _Pragma("unroll")                                                    \
        for (int j = 0; j < 2; ++j)                                          \
            acc[QM * 4 + i][QN * 2 + j] =                                    \
                __builtin_amdgcn_mfma_f32_16x16x32_bf16(                     \
                    a0_[i], b0_[j], acc[QM * 4 + i][QN * 2 + j], 0, 0, 0);   \
    _Pragma("unroll")                                                        \
    for (int i = 0; i < 4; ++i)                                              \
        _Pragma("unroll")                                                    \
        for (int j = 0; j < 2; ++j)                                          \
            acc[QM * 4 + i][QN * 2 + j] =                                    \
                __builtin_amdgcn_mfma_f32_16x16x32_bf16(                     \
                    a1_[i], b1_[j], acc[QM * 4 + i][QN * 2 + j], 0, 0, 0);   \
    __builtin_amdgcn_s_setprio(0);                                           \
  }

template<bool HASRES, bool GELUF, bool TRANSOUT>
__global__ __launch_bounds__(512)
void gemm8_k(const ushortT* __restrict__ A, long sA, int aMod,
             const ushortT* __restrict__ B, long sB,
             void* __restrict__ Cp, long sC,
             const float* __restrict__ R, long sR,
             int M, int N, int K, int gx, int gy)
{
    __shared__ ushortT smem[65536];
    const int nwg = gridDim.x;
    const int bid = blockIdx.x;
    const int lid = (bid & 7) * (nwg >> 3) + (bid >> 3);
    const int x = lid % gx;
    const int y = (lid / gx) % gy;
    const int z = lid / (gx * gy);
    const ushortT* Ab = A + (long)(z % aMod) * sA + (long)y * 256 * K;
    const ushortT* Bb = B + (long)z * sB + (long)x * 256 * K;
    const int tid = threadIdx.x;
    const int wv = tid >> 6, l = tid & 63;
    const int lrow = l & 15, lk = l >> 4;
    const int wr = wv >> 2, wc = wv & 3;
    f32x4 acc[8][4] = {};
    const int NT = K >> 6;

    auto stageAh = [&](int T, int qm) {
        ushortT* D = smem + (T & 1) * 32768;
        const int k0 = T << 6;
        #pragma unroll
        for (int t = 0; t < 2; ++t) {
            int r0 = wv * 16 + t * 8;
            int gr0 = ((r0 & 64) << 1) + qm * 64 + (r0 & 63);
            int gr = gr0 + (l >> 3);
            int gs = (l & 7) ^ (gr & 7);
            gl_lds16(Ab + (long)gr * K + k0 + gs * 8, D + gr0 * 64);
        }
    };
    auto stageBh = [&](int T, int qn) {
        ushortT* D = smem + (T & 1) * 32768 + 16384;
        const int k0 = T << 6;
        #pragma unroll
        for (int t = 0; t < 2; ++t) {
            int r0 = wv * 16 + t * 8;
            int gr0 = ((r0 >> 5) << 6) + qn * 32 + (r0 & 31);
            int gr = gr0 + (l >> 3);
            int gs = (l & 7) ^ (gr & 7);
            gl_lds16(Bb + (long)gr * K + k0 + gs * 8, D + gr0 * 64);
        }
    };

    stageAh(0, 0); stageAh(0, 1); stageBh(0, 0); stageBh(0, 1);
    if (NT > 1) {
        stageAh(1, 0); stageBh(1, 0);
        asm volatile("s_waitcnt vmcnt(4)" ::: "memory");
    } else {
        asm volatile("s_waitcnt vmcnt(0)" ::: "memory");
    }
    __builtin_amdgcn_s_barrier();

    for (int T = 0; T < NT; ++T) {
        const ushortT* As = smem + (T & 1) * 32768;
        const ushortT* Bs = As + 16384;
        const bool s1 = (T + 1 < NT), s2 = (T + 2 < NT);
        QPHASE(0, 0, if (s1) stageAh(T + 1, 1), );
        QPHASE(0, 1, if (s1) stageBh(T + 1, 1), );
        QPHASE(1, 0, if (s2) stageAh(T + 2, 0), );
        QPHASE(1, 1, if (s2) stageBh(T + 2, 0),
               if (s2) { asm volatile("s_waitcnt vmcnt(4)" ::: "memory"); }
               else    { asm volatile("s_waitcnt vmcnt(0)" ::: "memory"); });
    }

    const int m0g = y * 256 + wr * 128, n0g = x * 256 + wc * 64;
    if (!TRANSOUT) {
        float* Cf = (float*)Cp + (long)z * sC;
        #pragma unroll
        for (int ip = 0; ip < 8; ++ip)
            #pragma unroll
            for (int j = 0; j < 4; ++j)
                #pragma unroll
                for (int rg = 0; rg < 4; ++rg) {
                    long m = m0g + ip * 16 + lk * 4 + rg;
                    long n = n0g + j * 16 + lrow;
                    float v = acc[ip][j][rg];
                    if (GELUF) v = geluf(v);
                    if (HASRES) v += R[(long)z * sR + m * N + n];
                    Cf[m * N + n] = v;
                }
    } else {
        __syncthreads();
        ushortT* Ts = smem + wv * 4096;
        ushortT* CT = (ushortT*)Cp + (long)z * sC;
        #pragma unroll
        for (int s = 0; s < 2; ++s) {
            #pragma unroll
            for (int i2 = 0; i2 < 4; ++i2)
                #pragma unroll
                for (int j = 0; j < 4; ++j)
                    #pragma unroll
                    for (int rg = 0; rg < 4; ++rg) {
                        int ml = i2 * 16 + lk * 4 + rg;
                        int nl = j * 16 + lrow;
                        float v = acc[s * 4 + i2][j][rg];
                        if (GELUF) v = geluf(v);
                        Ts[nl * 64 + (((ml >> 3) ^ (nl & 7)) << 3) + (ml & 7)] = f2bf(v);
                    }
            #pragma unroll
            for (int p = 0; p < 8; ++p) {
                int nl = p * 8 + (l >> 3), mc = l & 7;
                uint4 d = *(const uint4*)&Ts[nl * 64 + ((mc ^ (nl & 7)) << 3)];
                *(uint4*)&CT[(long)(n0g + nl) * M + m0g + s * 64 + mc * 8] = d;
            }
        }
    }
}

// ------- pipelined bf16 GEMM: 3-slot, 2-PHASE per K-step, counted vmcnt (lin2) -------
// Per iter T: ph1 {8 ds_read ko=0; stageA(T+2)+stageBh(T+2,0); lgkm0; bar; 16 MFMA}
//             ph2 {8 ds_read ko=1; stageBh(T+2,1); vmcnt(6); lgkm0; bar; 16 MFMA}
// Slot-reuse safety: reads of slot T retire before each phase barrier (lgkmcnt 0);
// writes to slot (T+2)%3 happen after those barriers.
template<bool HASRES, bool GELUF, bool TRANSOUT>
__global__ __launch_bounds__(512)
void pgemm_k(const ushortT* __restrict__ A, long sA, int aMod,
             const ushortT* __restrict__ B, long sB,
             void* __restrict__ Cp, long sC,
             const float* __restrict__ R, long sR,
             int M, int N, int K, int gx, int gy)
{
    __shared__ ushortT smem[3 * 24576];
    const int nwg = gridDim.x;
    const int bid = blockIdx.x;
    const int lid = (bid & 7) * (nwg >> 3) + (bid >> 3);
    const int x = lid % gx;
    const int y = (lid / gx) % gy;
    const int z = lid / (gx * gy);
    const ushortT* Ab = A + (long)(z % aMod) * sA + (long)y * 128 * K;
    const ushortT* Bb = B + (long)z * sB + (long)x * 256 * K;
    const int tid = threadIdx.x;
    const int wv = tid >> 6, l = tid & 63;
    const int lrow = l & 15, lk = l >> 4;
    const int mb = (wv >> 2) * 64;
    const int nb = (wv & 3) * 64;
    f32x4 acc[4][4] = {};
    const int NT = K >> 6;

    auto stageA = [&](int T) {                    // 2 gl_lds
        ushortT* As = smem + (T % 3) * 24576;
        const int k0 = T << 6;
        #pragma unroll
        for (int t = 0; t < 2; ++t) {
            int r0 = wv * 16 + t * 8;
            int row = r0 + (l >> 3);
            int gs = (l & 7) ^ (row & 7);
            gl_lds16(Ab + (long)row * K + k0 + gs * 8, As + r0 * 64);
        }
    };
    auto stageBh = [&](int T, int h) {            // 2 gl_lds (16 B-rows)
        ushortT* Bs = smem + (T % 3) * 24576 + 8192;
        const int k0 = T << 6;
        #pragma unroll
        for (int t = 0; t < 2; ++t) {
            int r0 = wv * 32 + (h * 2 + t) * 8;
            int row = r0 + (l >> 3);
            int gs = (l & 7) ^ (row & 7);
            gl_lds16(Bb + (long)row * K + k0 + gs * 8, Bs + r0 * 64);
        }
    };

    stageA(0); stageBh(0, 0); stageBh(0, 1);
    if (NT > 1) {
        stageA(1); stageBh(1, 0); stageBh(1, 1);
        asm volatile("s_waitcnt vmcnt(6)" ::: "memory");
    } else {
        asm volatile("s_waitcnt vmcnt(0)" ::: "memory");
    }
    __builtin_amdgcn_s_barrier();

    for (int T = 0; T < NT; ++T) {
        const ushortT* As = smem + (T % 3) * 24576;
        const ushortT* Bs = As + 8192;
        const bool s1 = (T + 1 < NT), s2 = (T + 2 < NT);

        // ---- phase 1 (ko = 0) ----
        {
            bf16x8 af[4], bg[4];
            #pragma unroll
            for (int i = 0; i < 4; ++i) {
                int ra = mb + i * 16 + lrow;
                af[i] = *(const bf16x8*)&As[ra * 64 + ((lk) ^ (ra & 7)) * 8];
                int rb = nb + i * 16 + lrow;
                bg[i] = *(const bf16x8*)&Bs[rb * 64 + ((lk) ^ (rb & 7)) * 8];
            }
            if (s2) { stageA(T + 2); stageBh(T + 2, 0); }
            asm volatile("s_waitcnt lgkmcnt(0)" ::: "memory");
            __builtin_amdgcn_s_barrier();
            __builtin_amdgcn_s_setprio(1);
            #pragma unroll
            for (int i = 0; i < 4; ++i)
                #pragma unroll
                for (int j = 0; j < 4; ++j)
                    acc[i][j] = __builtin_amdgcn_mfma_f32_16x16x32_bf16(
                        af[i], bg[j], acc[i][j], 0, 0, 0);
            __builtin_amdgcn_s_setprio(0);
        }
        // ---- phase 2 (ko = 1) ----
        {
            bf16x8 af[4], bg[4];
            #pragma unroll
            for (int i = 0; i < 4; ++i) {
                int ra = mb + i * 16 + lrow;
                af[i] = *(const bf16x8*)&As[ra * 64 + ((lk + 4) ^ (ra & 7)) * 8];
                int rb = nb + i * 16 + lrow;
                bg[i] = *(const bf16x8*)&Bs[rb * 64 + ((lk + 4) ^ (rb & 7)) * 8];
            }
            if (s2) stageBh(T + 2, 1);
            if (s1) {
                if (s2) { asm volatile("s_waitcnt vmcnt(6)" ::: "memory"); }
                else    { asm volatile("s_waitcnt vmcnt(0)" ::: "memory"); }
            }
            asm volatile("s_waitcnt lgkmcnt(0)" ::: "memory");
            __builtin_amdgcn_s_barrier();
            __builtin_amdgcn_s_setprio(1);
            #pragma unroll
            for (int i = 0; i < 4; ++i)
                #pragma unroll
                for (int j = 0; j < 4; ++j)
                    acc[i][j] = __builtin_amdgcn_mfma_f32_16x16x32_bf16(
                        af[i], bg[j], acc[i][j], 0, 0, 0);
            __builtin_amdgcn_s_setprio(0);
        }
    }

    const int m0g = y * 128 + mb, n0g = x * 256 + nb;
    if (!TRANSOUT) {
        float* Cf = (float*)Cp + (long)z * sC;
        #pragma unroll
        for (int i = 0; i < 4; ++i)
            #pragma unroll
            for (int j = 0; j < 4; ++j)
                #pragma unroll
                for (int rg = 0; rg < 4; ++rg) {
                    long m = m0g + i * 16 + lk * 4 + rg;
                    long n = n0g + j * 16 + lrow;
                    float v = acc[i][j][rg];
                    if (GELUF) v = geluf(v);
                    if (HASRES) v += R[(long)z * sR + m * N + n];
                    Cf[m * N + n] = v;
                }
    } else {
        __syncthreads();
        ushortT* Ts = smem + wv * 4096;
        #pragma unroll
        for (int i = 0; i < 4; ++i)
            #pragma unroll
            for (int j = 0; j < 4; ++j)
                #pragma unroll
                for (int rg = 0; rg < 4; ++rg) {
                    int ml = i * 16 + lk * 4 + rg;
                    int nl = j * 16 + lrow;
                    float v = acc[i][j][rg];
                    if (GELUF) v = geluf(v);
                    Ts[nl * 64 + (((ml >> 3) ^ (nl & 7)) << 3) + (ml & 7)] = f2bf(v);
                }
        __syncthreads();
        ushortT* CT = (ushortT*)Cp + (long)z * sC;
        #pragma unroll
        for (int p = 0; p < 8; ++p) {
            int nl = p * 8 + (l >> 3), mc = l & 7;
            uint4 d = *(const uint4*)&Ts[nl * 64 + ((mc ^ (nl & 7)) << 3)];
            *(uint4*)&CT[(long)(n0g + nl) * M + m0g + mc * 8] = d;
        }
    }
}

// ---------------- fused-cast MFMA GEMM, simple 2-barrier (qproj/outproj) ----------------
template<bool HASRES, bool GELUF, bool TRANSOUT, bool ROPE>
__global__ __launch_bounds__(256)
void fgemm_k(const float* __restrict__ A, long sA, int aMod,
             const ushortT* __restrict__ B, long sB,
             void* __restrict__ Cp, long sC,
             const float* __restrict__ R, long sR,
             ushortT* __restrict__ Crot,
             const float* __restrict__ cosT, const float* __restrict__ sinT,
             int M, int N, int K, int gx, int gy)
{
    __shared__ ushortT smem[2 * 8192];
    ushortT* As = smem;
    ushortT* Bs = smem + 8192;
    const int nwg = gridDim.x;
    const int bid = blockIdx.x;
    const int lid = (bid & 7) * (nwg >> 3) + (bid >> 3);
    const int x = lid % gx;
    const int y = (lid / gx) % gy;
    const int z = lid / (gx * gy);
    const float*   Ab = A + (long)(z % aMod) * sA + (long)y * 128 * K;
    const ushortT* Bb = B + (long)z * sB + (long)x * 128 * K;
    const int tid = threadIdx.x;
    const int wv = tid >> 6, l = tid & 63;
    const int lrow = l & 15, lk = l >> 4;
    const int mb = (wv >> 1) * 64, nb = (wv & 1) * 64;
    const int arow = tid >> 3, agrp = tid & 7;
    f32x4 acc[4][4] = {};
    float4 a0[4], a1[4];
    const int NT = K >> 6;

    auto fetchA = [&](int k0) {
        #pragma unroll
        for (int c = 0; c < 4; ++c) {
            const float* src = Ab + (long)(arow + c * 32) * K + k0 + agrp * 8;
            a0[c] = *(const float4*)src;
            a1[c] = *(const float4*)(src + 4);
        }
    };
    auto commitA = [&]() {
        #pragma unroll
        for (int c = 0; c < 4; ++c) {
            int row = arow + c * 32;
            uint4 v;
            v.x = cvtpk(a0[c].x, a0[c].y);
            v.y = cvtpk(a0[c].z, a0[c].w);
            v.z = cvtpk(a1[c].x, a1[c].y);
            v.w = cvtpk(a1[c].z, a1[c].w);
            *(uint4*)&As[row * 64 + ((agrp ^ (row & 7)) << 3)] = v;
        }
    };
    auto stageB = [&](int k0) {
        #pragma unroll
        for (int t = 0; t < 4; ++t) {
            int r0 = wv * 32 + t * 8;
            int row = r0 + (l >> 3);
            int gs = (l & 7) ^ (row & 7);
            gl_lds16(Bb + (long)row * K + k0 + gs * 8, Bs + r0 * 64);
        }
    };
    auto compute = [&]() {
        #pragma unroll
        for (int ko = 0; ko < 2; ++ko) {
            bf16x8 af[4], bg[4];
            #pragma unroll
            for (int i = 0; i < 4; ++i) {
                int ra = mb + i * 16 + lrow;
                af[i] = *(const bf16x8*)&As[ra * 64 + ((lk + ko * 4) ^ (ra & 7)) * 8];
                int rb = nb + i * 16 + lrow;
                bg[i] = *(const bf16x8*)&Bs[rb * 64 + ((lk + ko * 4) ^ (rb & 7)) * 8];
            }
            #pragma unroll
            for (int i = 0; i < 4; ++i)
                #pragma unroll
                for (int j = 0; j < 4; ++j)
                    acc[i][j] = __builtin_amdgcn_mfma_f32_16x16x32_bf16(
                        af[i], bg[j], acc[i][j], 0, 0, 0);
        }
    };

    fetchA(0);
    for (int t = 0; t < NT; ++t) {
        if (t > 0) __syncthreads();
        stageB(t << 6);
        commitA();
        if (t + 1 < NT) fetchA((t + 1) << 6);
        __syncthreads();
        compute();
    }

    const int m0g = y * 128 + mb, n0g = x * 128 + nb;
    if (!TRANSOUT) {
        float* Cf = (float*)Cp + (long)z * sC;
        #pragma unroll
        for (int i = 0; i < 4; ++i)
            #pragma unroll
            for (int j = 0; j < 4; ++j)
                #pragma unroll
                for (int rg = 0; rg < 4; ++rg) {
                    long m = m0g + i * 16 + lk * 4 + rg;
                    long n = n0g + j * 16 + lrow;
                    float v = acc[i][j][rg];
                    if (GELUF) v = geluf(v);
                    if (HASRES) v += R[(long)z * sR + m * N + n];
                    Cf[m * N + n] = v;
                }
    } else {
        ushortT* Ts = smem + wv * 4096;
        __syncthreads();
        #pragma unroll
        for (int i = 0; i < 4; ++i)
            #pragma unroll
            for (int j = 0; j < 4; ++j)
                #pragma unroll
                for (int rg = 0; rg < 4; ++rg) {
                    int ml = i * 16 + lk * 4 + rg;
                    int nl = j * 16 + lrow;
                    float v = acc[i][j][rg];
                    if (GELUF) v = geluf(v);
                    Ts[nl * 64 + (((ml >> 3) ^ (nl & 7)) << 3) + (ml & 7)] = f2bf(v);
                }
        __syncthreads();
        ushortT* CT = (ushortT*)Cp + (long)z * sC;
        #pragma unroll
        for (int p = 0; p < 8; ++p) {
            int nl = p * 8 + (l >> 3), mc = l & 7;
            uint4 d = *(const uint4*)&Ts[nl * 64 + ((mc ^ (nl & 7)) << 3)];
            int wg = n0g + nl;
            int g0 = m0g + mc * 8;
            *(uint4*)&CT[(long)wg * M + g0] = d;
            if (ROPE) {
                ushortT* RT = Crot + (long)z * sC;
                int d0 = g0 & 63;
                if (d0 >= ROTD) {
                    *(uint4*)&RT[(long)wg * M + g0] = d;
                } else {
                    union { uint4 v; ushortT h8[8]; } in, ov;
                    in.v = d;
                    #pragma unroll
                    for (int j = 0; j < 8; j += 2) {
                        int i2 = (d0 + j) >> 1;
                        float cc = cosT[wg * 16 + i2], ss = sinT[wg * 16 + i2];
                        float a = bf2f(in.h8[j]), b = bf2f(in.h8[j + 1]);
                        ov.h8[j]     = f2bf(a * cc - b * ss);
                        ov.h8[j + 1] = f2bf(b * cc + a * ss);
                    }
                    *(uint4*)&RT[(long)wg * M + g0] = ov.v;
                }
            }
        }
    }
}

extern "C" void kernel_launch(void* const* d_in, const int* in_sizes, int n_in,
                              void* d_out, int out_size, void* d_ws, size_t ws_size,
                              hipStream_t stream)
{
    const float* x    = (const float*)d_in[0];
    const float* n1w  = (const float*)d_in[1];
    const float* n1b  = (const float*)d_in[2];
    const float* freqs= (const float*)d_in[3];
    const float* qw   = (const float*)d_in[4];
    const float* ow   = (const float*)d_in[5];
    const float* n2w  = (const float*)d_in[6];
    const float* n2b  = (const float*)d_in[7];
    const float* l1w  = (const float*)d_in[8];
    const float* l2w  = (const float*)d_in[9];
    float* out = (float*)d_out;
    char* wsb  = (char*)d_ws;
    const long MB = 1L << 20;

    ushortT* znT  = (ushortT*)(wsb +   0 * MB);   // 16MB (dead after qproj)
    ushortT* yT   = (ushortT*)(wsb +  16 * MB);   // 16MB (dead after attn)
    ushortT* rotT = (ushortT*)(wsb +  32 * MB);   // 16MB (dead after attn)
    ushortT* CfT  = (ushortT*)(wsb +  48 * MB);   // 16MB (dead after outproj)
    ushortT* wB   = (ushortT*)(wsb +   0 * MB);   // 64MB weight cast (l1w, then l2w)
    ushortT* zn2T = (ushortT*)(wsb +  64 * MB);   // 16MB
    ushortT* h1T  = (ushortT*)(wsb +  80 * MB);   // 64MB
    float*   cosT = (float*)  (wsb + 144 * MB);
    float*   sinT = cosT + WW * 16;

    rope_tab_k<<<32, 256, 0, stream>>>(freqs, cosT, sinT);

    // norm1: x -> znT (bf16 [w][f])
    normT_k<<<BB * CCH * 16, 1024, 0, stream>>>(x, n1w, n1b, znT);

    // qproj + fused RoPE: yT (raw) and rotT (rotated), both [bc][w][g]
    fgemm_k<false, false, true, true><<<512, 256, 0, stream>>>(
        qw,  (long)BINS * BINS, CCH,
        znT, (long)WW * BINS,
        yT,  (long)WW * BINS,
        nullptr, 0,
        rotT, cosT, sinT,
        BINS, WW, BINS, 4, 8);

    // MFMA flash attention -> CfT [bc][w][g]
    mattn_k<<<dim3(8, 256), 256, 0, stream>>>(rotT, yT, CfT);

    // outproj + residual: out = x + ow[c] @ CfT^T
    fgemm_k<true, false, false, false><<<512, 256, 0, stream>>>(
        ow,  (long)BINS * BINS, CCH,
        CfT, (long)WW * BINS,
        out, (long)BINS * WW,
        x,   (long)BINS * WW,
        nullptr, nullptr, nullptr,
        BINS, WW, BINS, 4, 8);

    // cast l1w -> bf16 (overwrites znT/yT/rotT/CfT region, all dead)
    wcast_k<<<16384, 256, 0, stream>>>(l1w, wB, 8L * BINS * EXPF * BINS);

    // norm2: out -> zn2T (bf16 [w][f])
    normT_k<<<BB * CCH * 16, 1024, 0, stream>>>(out, n2w, n2b, zn2T);

    // lin1 + GELU (quadrant-phased 256x256): h1T [w][4096]
    gemm8_k<false, true, true><<<512, 512, 0, stream>>>(
        wB,   (long)BINS * EXPF * BINS, CCH,
        zn2T, (long)WW * BINS,
        h1T,  (long)WW * BINS * EXPF,
        nullptr, 0,
        BINS * EXPF, WW, BINS, 2, 16);

    // cast l2w -> bf16 (overwrites l1w cast, dead after lin1)
    wcast_k<<<16384, 256, 0, stream>>>(l2w, wB, 8L * BINS * EXPF * BINS);

    // lin2 + residual (2-phase pipelined, in-place on out)
    pgemm_k<true, false, false><<<256, 512, 0, stream>>>(
        wB,  (long)BINS * BINS * EXPF, CCH,
        h1T, (long)WW * BINS * EXPF,
        out, (long)BINS * WW,
        out, (long)BINS * WW,
        BINS, WW, BINS * EXPF, 2, 8);
}

// Round 16
// 426.505 us; speedup vs baseline: 1.0947x; 1.0053x over previous
//
#include <hip/hip_runtime.h>
#include <math.h>

#define BB 2
#define CCH 8
#define BINS 1024
#define WW 512
#define HEADS 16
#define HD 64
#define ROTD 32
#define EXPF 4
#define NXE 8388608L   // B*C*BINS*W
#define NTW 32         // w-columns per norm block

typedef unsigned short ushortT;
typedef short bf16x8 __attribute__((ext_vector_type(8)));
typedef float f32x4 __attribute__((ext_vector_type(4)));

__device__ __forceinline__ ushortT f2bf(float f) {
    unsigned int u = __float_as_uint(f);
    u = (u + 0x7FFF + ((u >> 16) & 1)) >> 16;
    return (ushortT)u;
}
__device__ __forceinline__ float bf2f(ushortT h) {
    return __uint_as_float(((unsigned int)h) << 16);
}
__device__ __forceinline__ unsigned int cvtpk(float lo, float hi) {
    unsigned int r;
    asm("v_cvt_pk_bf16_f32 %0, %1, %2" : "=v"(r) : "v"(lo), "v"(hi));
    return r;
}
__device__ __forceinline__ float geluf(float x) {
    return 0.5f * x * (1.f + erff(x * 0.70710678118654752f));
}
__device__ __forceinline__ void gl_lds16(const ushortT* g, ushortT* l) {
    __builtin_amdgcn_global_load_lds(
        (const __attribute__((address_space(1))) unsigned int*)g,
        (__attribute__((address_space(3))) unsigned int*)l, 16, 0, 0);
}
// cast 8 contiguous fp32 -> 8 bf16 (uint4 store)
__device__ __forceinline__ void cast8(const float* s, ushortT* d) {
    float4 a = *(const float4*)s;
    float4 b = *(const float4*)(s + 4);
    uint4 v;
    v.x = cvtpk(a.x, a.y); v.y = cvtpk(a.z, a.w);
    v.z = cvtpk(b.x, b.y); v.w = cvtpk(b.z, b.w);
    *(uint4*)d = v;
}

// ---------------- frame norm over BINS, transposed bf16 out [w][f] ----------------
__global__ __launch_bounds__(1024)
void normT_k(const float* __restrict__ X, const float* __restrict__ wgt,
             const float* __restrict__ bia, ushortT* __restrict__ YT)
{
    __shared__ float tile[NTW][BINS + 1];
    __shared__ float red0[32][NTW], red1[32][NTW];
    __shared__ float ms[NTW], is[NTW];
    const int bc = blockIdx.x >> 4;
    const int w0 = (blockIdx.x & 15) * NTW;
    const int tid = threadIdx.x;
    const int w  = tid & (NTW - 1);
    const int fy = tid >> 5;
    const float* Xb = X + (long)bc * BINS * WW + w0;
    float s = 0.f, s2 = 0.f;
    for (int f = fy; f < BINS; f += 32) {
        float v = Xb[(long)f * WW + w];
        s += v; s2 += v * v;
        tile[w][f] = v;
    }
    red0[fy][w] = s; red1[fy][w] = s2;
    __syncthreads();
    if (tid < NTW) {
        float ss = 0.f, qq = 0.f;
        #pragma unroll
        for (int j = 0; j < 32; ++j) { ss += red0[j][tid]; qq += red1[j][tid]; }
        float m = ss * (1.f / BINS);
        float var = qq * (1.f / BINS) - m * m;
        ms[tid] = m; is[tid] = rsqrtf(var + 1e-5f);
    }
    __syncthreads();
    const int w2 = tid >> 5;
    const int c  = tid & 31;
    float m = ms[w2], inv = is[w2];
    ushortT* Yb = YT + ((long)bc * WW + w0 + w2) * BINS;
    #pragma unroll
    for (int jj = 0; jj < 4; ++jj) {
        int f0 = jj * 256 + c * 8;
        union { ushortT h[8]; uint4 v; } r;
        #pragma unroll
        for (int e = 0; e < 8; ++e) {
            int f = f0 + e;
            float v = (tile[w2][f] - m) * inv * wgt[f] + bia[f];
            r.h[e] = f2bf(v);
        }
        *(uint4*)&Yb[f0] = r.v;
    }
}

// ---------------- RoPE tables ----------------
__global__ void rope_tab_k(const float* __restrict__ freqs,
                           float* __restrict__ cosT, float* __restrict__ sinT)
{
    int idx = blockIdx.x * 256 + threadIdx.x;
    if (idx >= WW * 16) return;
    int w = idx >> 4, i = idx & 15;
    float ang = (float)w * freqs[i];
    cosT[idx] = cosf(ang);
    sinT[idx] = sinf(ang);
}

// ---------------- MFMA flash attention + fused l1w cast (epilogue) ----------------
__global__ __launch_bounds__(256)
void mattn_k(const ushortT* __restrict__ rotT, const ushortT* __restrict__ yT,
             ushortT* __restrict__ oT,
             const float* __restrict__ wsrc, ushortT* __restrict__ wdst)
{
    __shared__ ushortT Qs[64 * 64];
    __shared__ ushortT Ks[64 * 64];
    __shared__ ushortT Vs[64 * 72];
    __shared__ ushortT Ps[64 * 72];
    const int z = blockIdx.y;
    const int bc = z >> 4, h = z & 15;
    const int wq0 = blockIdx.x * 64;
    const int tid = threadIdx.x;
    const int wv = tid >> 6, l = tid & 63;
    const int lr = l & 15, lk = l >> 4;
    const long hbase = (long)bc * WW * 1024 + h * 64;

    #pragma unroll
    for (int p = 0; p < 2; ++p) {
        int r0 = p * 32 + wv * 8;
        int row = r0 + (l >> 3);
        int gs = (l & 7) ^ (row & 7);
        gl_lds16(rotT + hbase + (long)(wq0 + row) * 1024 + gs * 8, Qs + r0 * 64);
    }

    f32x4 oacc[4] = {};
    float mrow[4] = {-INFINITY, -INFINITY, -INFINITY, -INFINITY};
    float lrow[4] = {0.f, 0.f, 0.f, 0.f};

    for (int u0 = 0; u0 < WW; u0 += 64) {
        #pragma unroll
        for (int p = 0; p < 2; ++p) {
            int r0 = p * 32 + wv * 8;
            int row = r0 + (l >> 3);
            int gs = (l & 7) ^ (row & 7);
            gl_lds16(rotT + hbase + (long)(u0 + row) * 1024 + gs * 8, Ks + r0 * 64);
        }
        #pragma unroll
        for (int rep = 0; rep < 2; ++rep) {
            int ch = rep * 4 + wv;
            union { uint4 v; ushortT h8[8]; } tmp;
            tmp.v = *(const uint4*)(yT + hbase + (long)(u0 + l) * 1024 + ch * 8);
            #pragma unroll
            for (int j = 0; j < 8; ++j)
                Vs[(ch * 8 + j) * 72 + l] = tmp.h8[j];
        }
        __syncthreads();

        f32x4 sacc[4] = {};
        #pragma unroll
        for (int ko = 0; ko < 2; ++ko) {
            int ar = wv * 16 + lr;
            bf16x8 aq = *(const bf16x8*)&Qs[ar * 64 + (((ko * 4) + lk) ^ (ar & 7)) * 8];
            #pragma unroll
            for (int f = 0; f < 4; ++f) {
                int br = f * 16 + lr;
                bf16x8 bk = *(const bf16x8*)&Ks[br * 64 + (((ko * 4) + lk) ^ (br & 7)) * 8];
                sacc[f] = __builtin_amdgcn_mfma_f32_16x16x32_bf16(aq, bk, sacc[f], 0, 0, 0);
            }
        }

        #pragma unroll
        for (int rg = 0; rg < 4; ++rg) {
            float s0 = sacc[0][rg] * (1.f / 32.f);
            float s1 = sacc[1][rg] * (1.f / 32.f);
            float s2 = sacc[2][rg] * (1.f / 32.f);
            float s3 = sacc[3][rg] * (1.f / 32.f);
            float mx = fmaxf(fmaxf(s0, s1), fmaxf(s2, s3));
            mx = fmaxf(mx, __shfl_xor(mx, 1));
            mx = fmaxf(mx, __shfl_xor(mx, 2));
            mx = fmaxf(mx, __shfl_xor(mx, 4));
            mx = fmaxf(mx, __shfl_xor(mx, 8));
            float mnew = fmaxf(mrow[rg], mx);
            float al = __expf(mrow[rg] - mnew);
            float p0 = __expf(s0 - mnew), p1 = __expf(s1 - mnew);
            float p2 = __expf(s2 - mnew), p3 = __expf(s3 - mnew);
            float rs = p0 + p1 + p2 + p3;
            rs += __shfl_xor(rs, 1);
            rs += __shfl_xor(rs, 2);
            rs += __shfl_xor(rs, 4);
            rs += __shfl_xor(rs, 8);
            lrow[rg] = lrow[rg] * al + rs;
            mrow[rg] = mnew;
            oacc[0][rg] *= al; oacc[1][rg] *= al;
            oacc[2][rg] *= al; oacc[3][rg] *= al;
            int prow = wv * 16 + lk * 4 + rg;
            Ps[prow * 72 +  0 + lr] = f2bf(p0);
            Ps[prow * 72 + 16 + lr] = f2bf(p1);
            Ps[prow * 72 + 32 + lr] = f2bf(p2);
            Ps[prow * 72 + 48 + lr] = f2bf(p3);
        }
        asm volatile("s_waitcnt lgkmcnt(0)" ::: "memory");

        #pragma unroll
        for (int ko = 0; ko < 2; ++ko) {
            int ar = wv * 16 + lr;
            bf16x8 ap = *(const bf16x8*)&Ps[ar * 72 + ko * 32 + lk * 8];
            #pragma unroll
            for (int f = 0; f < 4; ++f) {
                bf16x8 bv = *(const bf16x8*)&Vs[(f * 16 + lr) * 72 + ko * 32 + lk * 8];
                oacc[f] = __builtin_amdgcn_mfma_f32_16x16x32_bf16(ap, bv, oacc[f], 0, 0, 0);
            }
        }
        __syncthreads();
    }

    #pragma unroll
    for (int rg = 0; rg < 4; ++rg) {
        float inv = 1.f / lrow[rg];
        int w = wq0 + wv * 16 + lk * 4 + rg;
        long b2 = (long)bc * WW * 1024 + (long)w * 1024 + h * 64;
        #pragma unroll
        for (int f = 0; f < 4; ++f)
            oT[b2 + f * 16 + lr] = f2bf(oacc[f][rg] * inv);
    }

    // fused l1w fp32->bf16 cast: 2048 blocks x 16384 elems (epilogue, off-loop)
    if (wsrc) {
        long wbase = ((long)z * 8 + blockIdx.x) * 16384 + tid * 8;
        #pragma unroll
        for (int p = 0; p < 8; ++p) {
            long i = wbase + (long)p * 2048;
            cast8(wsrc + i, wdst + i);
        }
    }
}

// ================= quadrant-phased 256x256 GEMM (lin1) + fused l2w cast =========
#define QPHASE(QM, QN, STAGES, VMW)                                          \
  {                                                                          \
    bf16x8 a0_[4], a1_[4], b0_[2], b1_[2];                                   \
    _Pragma("unroll")                                                        \
    for (int i = 0; i < 4; ++i) {                                            \
        int ra = wr * 128 + QM * 64 + i * 16 + lrow;                         \
        a0_[i] = *(const bf16x8*)&As[ra * 64 + ((lk    ) ^ (ra & 7)) * 8];   \
        a1_[i] = *(const bf16x8*)&As[ra * 64 + ((lk + 4) ^ (ra & 7)) * 8];   \
    }                                                                        \
    _Pragma("unroll")                                                        \
    for (int j = 0; j < 2; ++j) {                                            \
        int rb = wc * 64 + QN * 32 + j * 16 + lrow;                          \
        b0_[j] = *(const bf16x8*)&Bs[rb * 64 + ((lk    ) ^ (rb & 7)) * 8];   \
        b1_[j] = *(const bf16x8*)&Bs[rb * 64 + ((lk + 4) ^ (rb & 7)) * 8];   \
    }                                                                        \
    STAGES;                                                                  \
    VMW;                                                                     \
    asm volatile("s_waitcnt lgkmcnt(0)" ::: "memory");                       \
    __builtin_amdgcn_s_barrier();                                            \
    __builtin_amdgcn_s_setprio(1);                                           \
    _Pragma("unroll")                                                        \
    for (int i = 0; i < 4; ++i)                                              \
        _Pragma("unroll")                                                    \
        for (int j = 0; j < 2; ++j)                                          \
            acc[QM * 4 + i][QN * 2 + j] =                                    \
                __builtin_amdgcn_mfma_f32_16x16x32_bf16(                     \
                    a0_[i], b0_[j], acc[QM * 4 + i][QN * 2 + j], 0, 0, 0);   \
    _Pragma("unroll")                                                        \
    for (int i = 0; i < 4; ++i)                                              \
        _Pragma("unroll")                                                    \
        for (int j = 0; j < 2; ++j)                                          \
            acc[QM * 4 + i][QN * 2 + j] =                                    \
                __builtin_amdgcn_mfma_f32_16x16x32_bf16(                     \
                    a1_[i], b1_[j], acc[QM * 4 + i][QN * 2 + j], 0, 0, 0);   \
    __builtin_amdgcn_s_setprio(0);                                           \
  }

template<bool HASRES, bool GELUF, bool TRANSOUT>
__global__ __launch_bounds__(512)
void gemm8_k(const ushortT* __restrict__ A, long sA, int aMod,
             const ushortT* __restrict__ B, long sB,
             void* __restrict__ Cp, long sC,
             const float* __restrict__ R, long sR,
             const float* __restrict__ wsrc, ushortT* __restrict__ wdst,
             int M, int N, int K, int gx, int gy)
{
    __shared__ ushortT smem[65536];
    const int nwg = gridDim.x;
    const int bid = blockIdx.x;
    const int lid = (bid & 7) * (nwg >> 3) + (bid >> 3);
    const int x = lid % gx;
    const int y = (lid / gx) % gy;
    const int z = lid / (gx * gy);
    const ushortT* Ab = A + (long)(z % aMod) * sA + (long)y * 256 * K;
    const ushortT* Bb = B + (long)z * sB + (long)x * 256 * K;
    const int tid = threadIdx.x;
    const int wv = tid >> 6, l = tid & 63;
    const int lrow = l & 15, lk = l >> 4;
    const int wr = wv >> 2, wc = wv & 3;
    f32x4 acc[8][4] = {};
    const int NT = K >> 6;

    auto stageAh = [&](int T, int qm) {
        ushortT* D = smem + (T & 1) * 32768;
        const int k0 = T << 6;
        #pragma unroll
        for (int t = 0; t < 2; ++t) {
            int r0 = wv * 16 + t * 8;
            int gr0 = ((r0 & 64) << 1) + qm * 64 + (r0 & 63);
            int gr = gr0 + (l >> 3);
            int gs = (l & 7) ^ (gr & 7);
            gl_lds16(Ab + (long)gr * K + k0 + gs * 8, D + gr0 * 64);
        }
    };
    auto stageBh = [&](int T, int qn) {
        ushortT* D = smem + (T & 1) * 32768 + 16384;
        const int k0 = T << 6;
        #pragma unroll
        for (int t = 0; t < 2; ++t) {
            int r0 = wv * 16 + t * 8;
            int gr0 = ((r0 >> 5) << 6) + qn * 32 + (r0 & 31);
            int gr = gr0 + (l >> 3);
            int gs = (l & 7) ^ (gr & 7);
            gl_lds16(Bb + (long)gr * K + k0 + gs * 8, D + gr0 * 64);
        }
    };

    stageAh(0, 0); stageAh(0, 1); stageBh(0, 0); stageBh(0, 1);
    if (NT > 1) {
        stageAh(1, 0); stageBh(1, 0);
        asm volatile("s_waitcnt vmcnt(4)" ::: "memory");
    } else {
        asm volatile("s_waitcnt vmcnt(0)" ::: "memory");
    }
    __builtin_amdgcn_s_barrier();

    for (int T = 0; T < NT; ++T) {
        const ushortT* As = smem + (T & 1) * 32768;
        const ushortT* Bs = As + 16384;
        const bool s1 = (T + 1 < NT), s2 = (T + 2 < NT);
        QPHASE(0, 0, if (s1) stageAh(T + 1, 1), );
        QPHASE(0, 1, if (s1) stageBh(T + 1, 1), );
        QPHASE(1, 0, if (s2) stageAh(T + 2, 0), );
        QPHASE(1, 1, if (s2) stageBh(T + 2, 0),
               if (s2) { asm volatile("s_waitcnt vmcnt(4)" ::: "memory"); }
               else    { asm volatile("s_waitcnt vmcnt(0)" ::: "memory"); });
    }

    const int m0g = y * 256 + wr * 128, n0g = x * 256 + wc * 64;
    if (!TRANSOUT) {
        float* Cf = (float*)Cp + (long)z * sC;
        #pragma unroll
        for (int ip = 0; ip < 8; ++ip)
            #pragma unroll
            for (int j = 0; j < 4; ++j)
                #pragma unroll
                for (int rg = 0; rg < 4; ++rg) {
                    long m = m0g + ip * 16 + lk * 4 + rg;
                    long n = n0g + j * 16 + lrow;
                    float v = acc[ip][j][rg];
                    if (GELUF) v = geluf(v);
                    if (HASRES) v += R[(long)z * sR + m * N + n];
                    Cf[m * N + n] = v;
                }
    } else {
        __syncthreads();
        ushortT* Ts = smem + wv * 4096;
        ushortT* CT = (ushortT*)Cp + (long)z * sC;
        #pragma unroll
        for (int s = 0; s < 2; ++s) {
            #pragma unroll
            for (int i2 = 0; i2 < 4; ++i2)
                #pragma unroll
                for (int j = 0; j < 4; ++j)
                    #pragma unroll
                    for (int rg = 0; rg < 4; ++rg) {
                        int ml = i2 * 16 + lk * 4 + rg;
                        int nl = j * 16 + lrow;
                        float v = acc[s * 4 + i2][j][rg];
                        if (GELUF) v = geluf(v);
                        Ts[nl * 64 + (((ml >> 3) ^ (nl & 7)) << 3) + (ml & 7)] = f2bf(v);
                    }
            #pragma unroll
            for (int p = 0; p < 8; ++p) {
                int nl = p * 8 + (l >> 3), mc = l & 7;
                uint4 d = *(const uint4*)&Ts[nl * 64 + ((mc ^ (nl & 7)) << 3)];
                *(uint4*)&CT[(long)(n0g + nl) * M + m0g + s * 64 + mc * 8] = d;
            }
        }
    }

    // fused l2w fp32->bf16 cast: 512 blocks x 65536 elems (epilogue, off-loop)
    if (wsrc) {
        long wbase = (long)bid * 65536 + tid * 8;
        #pragma unroll
        for (int p = 0; p < 16; ++p) {
            long i = wbase + (long)p * 4096;
            cast8(wsrc + i, wdst + i);
        }
    }
}

// ------- pipelined bf16 GEMM: 3-slot, 2-PHASE per K-step, counted vmcnt (lin2) -------
template<bool HASRES, bool GELUF, bool TRANSOUT>
__global__ __launch_bounds__(512)
void pgemm_k(const ushortT* __restrict__ A, long sA, int aMod,
             const ushortT* __restrict__ B, long sB,
             void* __restrict__ Cp, long sC,
             const float* __restrict__ R, long sR,
             int M, int N, int K, int gx, int gy)
{
    __shared__ ushortT smem[3 * 24576];
    const int nwg = gridDim.x;
    const int bid = blockIdx.x;
    const int lid = (bid & 7) * (nwg >> 3) + (bid >> 3);
    const int x = lid % gx;
    const int y = (lid / gx) % gy;
    const int z = lid / (gx * gy);
    const ushortT* Ab = A + (long)(z % aMod) * sA + (long)y * 128 * K;
    const ushortT* Bb = B + (long)z * sB + (long)x * 256 * K;
    const int tid = threadIdx.x;
    const int wv = tid >> 6, l = tid & 63;
    const int lrow = l & 15, lk = l >> 4;
    const int mb = (wv >> 2) * 64;
    const int nb = (wv & 3) * 64;
    f32x4 acc[4][4] = {};
    const int NT = K >> 6;

    auto stageA = [&](int T) {
        ushortT* As = smem + (T % 3) * 24576;
        const int k0 = T << 6;
        #pragma unroll
        for (int t = 0; t < 2; ++t) {
            int r0 = wv * 16 + t * 8;
            int row = r0 + (l >> 3);
            int gs = (l & 7) ^ (row & 7);
            gl_lds16(Ab + (long)row * K + k0 + gs * 8, As + r0 * 64);
        }
    };
    auto stageBh = [&](int T, int h) {
        ushortT* Bs = smem + (T % 3) * 24576 + 8192;
        const int k0 = T << 6;
        #pragma unroll
        for (int t = 0; t < 2; ++t) {
            int r0 = wv * 32 + (h * 2 + t) * 8;
            int row = r0 + (l >> 3);
            int gs = (l & 7) ^ (row & 7);
            gl_lds16(Bb + (long)row * K + k0 + gs * 8, Bs + r0 * 64);
        }
    };

    stageA(0); stageBh(0, 0); stageBh(0, 1);
    if (NT > 1) {
        stageA(1); stageBh(1, 0); stageBh(1, 1);
        asm volatile("s_waitcnt vmcnt(6)" ::: "memory");
    } else {
        asm volatile("s_waitcnt vmcnt(0)" ::: "memory");
    }
    __builtin_amdgcn_s_barrier();

    for (int T = 0; T < NT; ++T) {
        const ushortT* As = smem + (T % 3) * 24576;
        const ushortT* Bs = As + 8192;
        const bool s1 = (T + 1 < NT), s2 = (T + 2 < NT);

        {   // ---- phase 1 (ko = 0) ----
            bf16x8 af[4], bg[4];
            #pragma unroll
            for (int i = 0; i < 4; ++i) {
                int ra = mb + i * 16 + lrow;
                af[i] = *(const bf16x8*)&As[ra * 64 + ((lk) ^ (ra & 7)) * 8];
                int rb = nb + i * 16 + lrow;
                bg[i] = *(const bf16x8*)&Bs[rb * 64 + ((lk) ^ (rb & 7)) * 8];
            }
            if (s2) { stageA(T + 2); stageBh(T + 2, 0); }
            asm volatile("s_waitcnt lgkmcnt(0)" ::: "memory");
            __builtin_amdgcn_s_barrier();
            __builtin_amdgcn_s_setprio(1);
            #pragma unroll
            for (int i = 0; i < 4; ++i)
                #pragma unroll
                for (int j = 0; j < 4; ++j)
                    acc[i][j] = __builtin_amdgcn_mfma_f32_16x16x32_bf16(
                        af[i], bg[j], acc[i][j], 0, 0, 0);
            __builtin_amdgcn_s_setprio(0);
        }
        {   // ---- phase 2 (ko = 1) ----
            bf16x8 af[4], bg[4];
            #pragma unroll
            for (int i = 0; i < 4; ++i) {
                int ra = mb + i * 16 + lrow;
                af[i] = *(const bf16x8*)&As[ra * 64 + ((lk + 4) ^ (ra & 7)) * 8];
                int rb = nb + i * 16 + lrow;
                bg[i] = *(const bf16x8*)&Bs[rb * 64 + ((lk + 4) ^ (rb & 7)) * 8];
            }
            if (s2) stageBh(T + 2, 1);
            if (s1) {
                if (s2) { asm volatile("s_waitcnt vmcnt(6)" ::: "memory"); }
                else    { asm volatile("s_waitcnt vmcnt(0)" ::: "memory"); }
            }
            asm volatile("s_waitcnt lgkmcnt(0)" ::: "memory");
            __builtin_amdgcn_s_barrier();
            __builtin_amdgcn_s_setprio(1);
            #pragma unroll
            for (int i = 0; i < 4; ++i)
                #pragma unroll
                for (int j = 0; j < 4; ++j)
                    acc[i][j] = __builtin_amdgcn_mfma_f32_16x16x32_bf16(
                        af[i], bg[j], acc[i][j], 0, 0, 0);
            __builtin_amdgcn_s_setprio(0);
        }
    }

    const int m0g = y * 128 + mb, n0g = x * 256 + nb;
    if (!TRANSOUT) {
        float* Cf = (float*)Cp + (long)z * sC;
        #pragma unroll
        for (int i = 0; i < 4; ++i)
            #pragma unroll
            for (int j = 0; j < 4; ++j)
                #pragma unroll
                for (int rg = 0; rg < 4; ++rg) {
                    long m = m0g + i * 16 + lk * 4 + rg;
                    long n = n0g + j * 16 + lrow;
                    float v = acc[i][j][rg];
                    if (GELUF) v = geluf(v);
                    if (HASRES) v += R[(long)z * sR + m * N + n];
                    Cf[m * N + n] = v;
                }
    } else {
        __syncthreads();
        ushortT* Ts = smem + wv * 4096;
        #pragma unroll
        for (int i = 0; i < 4; ++i)
            #pragma unroll
            for (int j = 0; j < 4; ++j)
                #pragma unroll
                for (int rg = 0; rg < 4; ++rg) {
                    int ml = i * 16 + lk * 4 + rg;
                    int nl = j * 16 + lrow;
                    float v = acc[i][j][rg];
                    if (GELUF) v = geluf(v);
                    Ts[nl * 64 + (((ml >> 3) ^ (nl & 7)) << 3) + (ml & 7)] = f2bf(v);
                }
        __syncthreads();
        ushortT* CT = (ushortT*)Cp + (long)z * sC;
        #pragma unroll
        for (int p = 0; p < 8; ++p) {
            int nl = p * 8 + (l >> 3), mc = l & 7;
            uint4 d = *(const uint4*)&Ts[nl * 64 + ((mc ^ (nl & 7)) << 3)];
            *(uint4*)&CT[(long)(n0g + nl) * M + m0g + mc * 8] = d;
        }
    }
}

// ---------------- fused-cast MFMA GEMM, simple 2-barrier (qproj/outproj) ----------------
template<bool HASRES, bool GELUF, bool TRANSOUT, bool ROPE>
__global__ __launch_bounds__(256)
void fgemm_k(const float* __restrict__ A, long sA, int aMod,
             const ushortT* __restrict__ B, long sB,
             void* __restrict__ Cp, long sC,
             const float* __restrict__ R, long sR,
             ushortT* __restrict__ Crot,
             const float* __restrict__ cosT, const float* __restrict__ sinT,
             int M, int N, int K, int gx, int gy)
{
    __shared__ ushortT smem[2 * 8192];
    ushortT* As = smem;
    ushortT* Bs = smem + 8192;
    const int nwg = gridDim.x;
    const int bid = blockIdx.x;
    const int lid = (bid & 7) * (nwg >> 3) + (bid >> 3);
    const int x = lid % gx;
    const int y = (lid / gx) % gy;
    const int z = lid / (gx * gy);
    const float*   Ab = A + (long)(z % aMod) * sA + (long)y * 128 * K;
    const ushortT* Bb = B + (long)z * sB + (long)x * 128 * K;
    const int tid = threadIdx.x;
    const int wv = tid >> 6, l = tid & 63;
    const int lrow = l & 15, lk = l >> 4;
    const int mb = (wv >> 1) * 64, nb = (wv & 1) * 64;
    const int arow = tid >> 3, agrp = tid & 7;
    f32x4 acc[4][4] = {};
    float4 a0[4], a1[4];
    const int NT = K >> 6;

    auto fetchA = [&](int k0) {
        #pragma unroll
        for (int c = 0; c < 4; ++c) {
            const float* src = Ab + (long)(arow + c * 32) * K + k0 + agrp * 8;
            a0[c] = *(const float4*)src;
            a1[c] = *(const float4*)(src + 4);
        }
    };
    auto commitA = [&]() {
        #pragma unroll
        for (int c = 0; c < 4; ++c) {
            int row = arow + c * 32;
            uint4 v;
            v.x = cvtpk(a0[c].x, a0[c].y);
            v.y = cvtpk(a0[c].z, a0[c].w);
            v.z = cvtpk(a1[c].x, a1[c].y);
            v.w = cvtpk(a1[c].z, a1[c].w);
            *(uint4*)&As[row * 64 + ((agrp ^ (row & 7)) << 3)] = v;
        }
    };
    auto stageB = [&](int k0) {
        #pragma unroll
        for (int t = 0; t < 4; ++t) {
            int r0 = wv * 32 + t * 8;
            int row = r0 + (l >> 3);
            int gs = (l & 7) ^ (row & 7);
            gl_lds16(Bb + (long)row * K + k0 + gs * 8, Bs + r0 * 64);
        }
    };
    auto compute = [&]() {
        #pragma unroll
        for (int ko = 0; ko < 2; ++ko) {
            bf16x8 af[4], bg[4];
            #pragma unroll
            for (int i = 0; i < 4; ++i) {
                int ra = mb + i * 16 + lrow;
                af[i] = *(const bf16x8*)&As[ra * 64 + ((lk + ko * 4) ^ (ra & 7)) * 8];
                int rb = nb + i * 16 + lrow;
                bg[i] = *(const bf16x8*)&Bs[rb * 64 + ((lk + ko * 4) ^ (rb & 7)) * 8];
            }
            #pragma unroll
            for (int i = 0; i < 4; ++i)
                #pragma unroll
                for (int j = 0; j < 4; ++j)
                    acc[i][j] = __builtin_amdgcn_mfma_f32_16x16x32_bf16(
                        af[i], bg[j], acc[i][j], 0, 0, 0);
        }
    };

    fetchA(0);
    for (int t = 0; t < NT; ++t) {
        if (t > 0) __syncthreads();
        stageB(t << 6);
        commitA();
        if (t + 1 < NT) fetchA((t + 1) << 6);
        __syncthreads();
        compute();
    }

    const int m0g = y * 128 + mb, n0g = x * 128 + nb;
    if (!TRANSOUT) {
        float* Cf = (float*)Cp + (long)z * sC;
        #pragma unroll
        for (int i = 0; i < 4; ++i)
            #pragma unroll
            for (int j = 0; j < 4; ++j)
                #pragma unroll
                for (int rg = 0; rg < 4; ++rg) {
                    long m = m0g + i * 16 + lk * 4 + rg;
                    long n = n0g + j * 16 + lrow;
                    float v = acc[i][j][rg];
                    if (GELUF) v = geluf(v);
                    if (HASRES) v += R[(long)z * sR + m * N + n];
                    Cf[m * N + n] = v;
                }
    } else {
        ushortT* Ts = smem + wv * 4096;
        __syncthreads();
        #pragma unroll
        for (int i = 0; i < 4; ++i)
            #pragma unroll
            for (int j = 0; j < 4; ++j)
                #pragma unroll
                for (int rg = 0; rg < 4; ++rg) {
                    int ml = i * 16 + lk * 4 + rg;
                    int nl = j * 16 + lrow;
                    float v = acc[i][j][rg];
                    if (GELUF) v = geluf(v);
                    Ts[nl * 64 + (((ml >> 3) ^ (nl & 7)) << 3) + (ml & 7)] = f2bf(v);
                }
        __syncthreads();
        ushortT* CT = (ushortT*)Cp + (long)z * sC;
        #pragma unroll
        for (int p = 0; p < 8; ++p) {
            int nl = p * 8 + (l >> 3), mc = l & 7;
            uint4 d = *(const uint4*)&Ts[nl * 64 + ((mc ^ (nl & 7)) << 3)];
            int wg = n0g + nl;
            int g0 = m0g + mc * 8;
            *(uint4*)&CT[(long)wg * M + g0] = d;
            if (ROPE) {
                ushortT* RT = Crot + (long)z * sC;
                int d0 = g0 & 63;
                if (d0 >= ROTD) {
                    *(uint4*)&RT[(long)wg * M + g0] = d;
                } else {
                    union { uint4 v; ushortT h8[8]; } in, ov;
                    in.v = d;
                    #pragma unroll
                    for (int j = 0; j < 8; j += 2) {
                        int i2 = (d0 + j) >> 1;
                        float cc = cosT[wg * 16 + i2], ss = sinT[wg * 16 + i2];
                        float a = bf2f(in.h8[j]), b = bf2f(in.h8[j + 1]);
                        ov.h8[j]     = f2bf(a * cc - b * ss);
                        ov.h8[j + 1] = f2bf(b * cc + a * ss);
                    }
                    *(uint4*)&RT[(long)wg * M + g0] = ov.v;
                }
            }
        }
    }
}

extern "C" void kernel_launch(void* const* d_in, const int* in_sizes, int n_in,
                              void* d_out, int out_size, void* d_ws, size_t ws_size,
                              hipStream_t stream)
{
    const float* x    = (const float*)d_in[0];
    const float* n1w  = (const float*)d_in[1];
    const float* n1b  = (const float*)d_in[2];
    const float* freqs= (const float*)d_in[3];
    const float* qw   = (const float*)d_in[4];
    const float* ow   = (const float*)d_in[5];
    const float* n2w  = (const float*)d_in[6];
    const float* n2b  = (const float*)d_in[7];
    const float* l1w  = (const float*)d_in[8];
    const float* l2w  = (const float*)d_in[9];
    float* out = (float*)d_out;
    char* wsb  = (char*)d_ws;
    const long MB = 1L << 20;

    ushortT* znT  = (ushortT*)(wsb +   0 * MB);   // dead after qproj
    ushortT* yT   = (ushortT*)(wsb +  16 * MB);   // dead after attn
    ushortT* rotT = (ushortT*)(wsb +  32 * MB);   // dead after attn
    ushortT* CfT  = (ushortT*)(wsb +  48 * MB);   // dead after outproj
    ushortT* zn2T = (ushortT*)(wsb +  64 * MB);
    ushortT* h1T  = (ushortT*)(wsb +  80 * MB);   // 80-144
    ushortT* wB1  = (ushortT*)(wsb + 144 * MB);   // l1w bf16 (cast in attn)
    ushortT* wB2  = (ushortT*)(wsb +   0 * MB);   // l2w bf16 (cast in lin1; 0-64 dead then)
    float*   cosT = (float*)  (wsb + 208 * MB);
    float*   sinT = cosT + WW * 16;

    rope_tab_k<<<32, 256, 0, stream>>>(freqs, cosT, sinT);

    // norm1: x -> znT (bf16 [w][f])
    normT_k<<<BB * CCH * 16, 1024, 0, stream>>>(x, n1w, n1b, znT);

    // qproj + fused RoPE: yT (raw) and rotT (rotated), both [bc][w][g]
    fgemm_k<false, false, true, true><<<512, 256, 0, stream>>>(
        qw,  (long)BINS * BINS, CCH,
        znT, (long)WW * BINS,
        yT,  (long)WW * BINS,
        nullptr, 0,
        rotT, cosT, sinT,
        BINS, WW, BINS, 4, 8);

    // MFMA flash attention -> CfT; epilogue casts l1w -> wB1
    mattn_k<<<dim3(8, 256), 256, 0, stream>>>(rotT, yT, CfT, l1w, wB1);

    // outproj + residual: out = x + ow[c] @ CfT^T
    fgemm_k<true, false, false, false><<<512, 256, 0, stream>>>(
        ow,  (long)BINS * BINS, CCH,
        CfT, (long)WW * BINS,
        out, (long)BINS * WW,
        x,   (long)BINS * WW,
        nullptr, nullptr, nullptr,
        BINS, WW, BINS, 4, 8);

    // norm2: out -> zn2T (bf16 [w][f])
    normT_k<<<BB * CCH * 16, 1024, 0, stream>>>(out, n2w, n2b, zn2T);

    // lin1 + GELU (quadrant-phased): h1T [w][4096]; epilogue casts l2w -> wB2
    gemm8_k<false, true, true><<<512, 512, 0, stream>>>(
        wB1,  (long)BINS * EXPF * BINS, CCH,
        zn2T, (long)WW * BINS,
        h1T,  (long)WW * BINS * EXPF,
        nullptr, 0,
        l2w, wB2,
        BINS * EXPF, WW, BINS, 2, 16);

    // lin2 + residual (2-phase pipelined, in-place on out)
    pgemm_k<true, false, false><<<256, 512, 0, stream>>>(
        wB2, (long)BINS * BINS * EXPF, CCH,
        h1T, (long)WW * BINS * EXPF,
        out, (long)BINS * WW,
        out, (long)BINS * WW,
        BINS, WW, BINS * EXPF, 2, 8);
}